// Round 5
// baseline (295.149 us; speedup 1.0000x reference)
//
#include <hip/hip_runtime.h>
#include <cstdint>

// ContextualAttention on MI355X (gfx950), all-bf16 MFMA pipeline.
// R5: GEMMs -> conflict-free column-chunk LDS + 3-buffer counted-vmcnt pipeline
//     (T4: never drain vmcnt(0) in the main loop); attn grid reordered so the
//     8 q-tiles of one (b,h) share an XCD's L2 (kills 3.4x KV HBM re-read).

typedef unsigned short u16;
typedef __attribute__((ext_vector_type(8))) short bf16x8;
typedef __attribute__((ext_vector_type(4))) float f32x4;
typedef __attribute__((ext_vector_type(16))) float f32x16;
typedef __attribute__((ext_vector_type(4))) unsigned short u16x4;
typedef __attribute__((ext_vector_type(2))) unsigned int u32x2;

#define GLDS(gsrc, ldst)                                                              \
  __builtin_amdgcn_global_load_lds(                                                   \
      (const __attribute__((address_space(1))) unsigned int*)(gsrc),                  \
      (__attribute__((address_space(3))) unsigned int*)(ldst), 16, 0, 0)

__device__ __forceinline__ u16 f2bf(float x) {
  unsigned int u = __float_as_uint(x);
  u += 0x7fffu + ((u >> 16) & 1u);
  return (u16)(u >> 16);
}

// packed f32x2 -> bf16x2 (RNE), single VOP3 (T12 recipe; no builtin on gfx950)
__device__ __forceinline__ unsigned cvt_pk_bf16(float lo, float hi) {
  unsigned r;
  asm("v_cvt_pk_bf16_f32 %0, %1, %2" : "=v"(r) : "v"(lo), "v"(hi));
  return r;
}

__device__ __forceinline__ f32x4 mfma16(bf16x8 a, bf16x8 b, f32x4 c) {
  return __builtin_amdgcn_mfma_f32_16x16x32_bf16(a, b, c, 0, 0, 0);
}
__device__ __forceinline__ f32x16 mfma32(bf16x8 a, bf16x8 b, f32x16 c) {
  return __builtin_amdgcn_mfma_f32_32x32x16_bf16(a, b, c, 0, 0, 0);
}

// ---------------- cast kernels ----------------

__global__ __launch_bounds__(256) void cast_concat(const float* __restrict__ x,
                                                   const float* __restrict__ c,
                                                   u16* __restrict__ o) {
  const int n4 = (8 << 20) / 4;  // B*T*E / 4
  for (int i = blockIdx.x * blockDim.x + threadIdx.x; i < n4; i += gridDim.x * blockDim.x) {
    int elem = i * 4;
    int b = elem >> 21;
    int rem = elem & ((1 << 21) - 1);
    int r = rem >> 10;
    int e = rem & 1023;
    const float* src = (r < 1024) ? (x + ((((size_t)(b << 10)) + r) << 10) + e)
                                  : (c + ((((size_t)(b << 10)) + (r - 1024)) << 10) + e);
    float4 v = *(const float4*)src;
    u16x4 ov;
    ov.x = f2bf(v.x); ov.y = f2bf(v.y); ov.z = f2bf(v.z); ov.w = f2bf(v.w);
    *(u16x4*)(o + elem) = ov;
  }
}

__global__ __launch_bounds__(256) void cast_w(const float* __restrict__ w0,
                                              const float* __restrict__ w1,
                                              const float* __restrict__ w2,
                                              const float* __restrict__ w3,
                                              u16* __restrict__ o) {
  const int n4 = (4 << 20) / 4;
  for (int i = blockIdx.x * blockDim.x + threadIdx.x; i < n4; i += gridDim.x * blockDim.x) {
    int elem = i * 4;
    int sel = elem >> 20;
    int loc = elem & ((1 << 20) - 1);
    const float* s = (sel == 0) ? w0 : (sel == 1) ? w1 : (sel == 2) ? w2 : w3;
    float4 v = *(const float4*)(s + loc);
    u16x4 ov;
    ov.x = f2bf(v.x); ov.y = f2bf(v.y); ov.z = f2bf(v.z); ov.w = f2bf(v.w);
    *(u16x4*)(o + elem) = ov;
  }
}

// ---------------- merged QKV GEMM: 128x128 tile, BK=32 ----------------
// LDS: column-chunk layout, conflict-free: addr = kchunk*2048 + row*16.
// 3-buffer pipeline, counted vmcnt(4) (4 GLDS per wave per stage batch).
// grid (64, 24). ny>>3: 0=Q (LN epi, compacted rows), 1=K (LN epi), 2=V (transposed).

__global__ __launch_bounds__(256)
void gemm_qkv(const u16* __restrict__ XCB, const u16* __restrict__ Wall,
              u16* __restrict__ QBB, u16* __restrict__ KBB, u16* __restrict__ VT,
              const float* __restrict__ qg, const float* __restrict__ qb,
              const float* __restrict__ kg, const float* __restrict__ kb,
              float sQ, float sK) {
  const int ny = blockIdx.y;
  const int which = ny >> 3;
  const int m0 = blockIdx.x << 7;
  if (which == 0 && (m0 & 2047) >= 1024) return;  // Q only from x rows
  const int n0 = (ny & 7) << 7;
  const u16* Bw = Wall + ((size_t)which << 20);
  const int K = 1024, N = 1024;

  __shared__ alignas(16) u16 lAm[3][128 * 32];  // 24 KB
  __shared__ alignas(16) u16 lBm[3][128 * 32];  // 24 KB
  const int tid = threadIdx.x;
  const int wv = tid >> 6, l = tid & 63, g = l >> 4, c16 = l & 15;
  const int wr = wv >> 1, wc = wv & 1;

  f32x4 acc[4][4];
  const f32x4 z4 = {0.f, 0.f, 0.f, 0.f};
#pragma unroll
  for (int i = 0; i < 4; ++i)
#pragma unroll
    for (int j = 0; j < 4; ++j) acc[i][j] = z4;

  // staging: wave wv owns k-chunk wv; lane l = row. Linear LDS dest, per-lane src.
  const u16* aSrc = XCB + (size_t)(m0 + l) * K + wv * 8;
  const u16* bSrc = Bw + (size_t)(n0 + l) * K + wv * 8;
  char* ldA = (char*)lAm;
  char* ldB = (char*)lBm;

#define STAGE_G(bi, kof)                                   \
  {                                                        \
    char* dA = ldA + (bi)*8192 + wv * 2048;                \
    char* dB = ldB + (bi)*8192 + wv * 2048;                \
    GLDS(aSrc + (kof), dA);                                \
    GLDS(aSrc + (size_t)64 * K + (kof), dA + 1024);        \
    GLDS(bSrc + (kof), dB);                                \
    GLDS(bSrc + (size_t)64 * K + (kof), dB + 1024);        \
  }

  STAGE_G(0, 0);
  STAGE_G(1, 32);
  int cb = 0, sb = 2;
  for (int kt = 0; kt < 32; ++kt) {
    if (kt < 31) {
      asm volatile("s_waitcnt vmcnt(4)" ::: "memory");
    } else {
      asm volatile("s_waitcnt vmcnt(0)" ::: "memory");
    }
    __builtin_amdgcn_s_barrier();
    if (kt + 2 < 32) STAGE_G(sb, (kt + 2) << 5);
    const char* bA = ldA + cb * 8192;
    const char* bB = ldB + cb * 8192;
    bf16x8 af[4], bfr[4];
#pragma unroll
    for (int mi = 0; mi < 4; ++mi)
      af[mi] = *(const bf16x8*)(bA + g * 2048 + (wr * 64 + mi * 16 + c16) * 16);
#pragma unroll
    for (int ni = 0; ni < 4; ++ni)
      bfr[ni] = *(const bf16x8*)(bB + g * 2048 + (wc * 64 + ni * 16 + c16) * 16);
    __builtin_amdgcn_s_setprio(1);
#pragma unroll
    for (int mi = 0; mi < 4; ++mi)
#pragma unroll
      for (int ni = 0; ni < 4; ++ni)
        acc[mi][ni] = mfma16(af[mi], bfr[ni], acc[mi][ni]);
    __builtin_amdgcn_s_setprio(0);
    cb = cb == 2 ? 0 : cb + 1;
    sb = sb == 2 ? 0 : sb + 1;
  }
#undef STAGE_G

  // ---- epilogues ----  C layout: col = l&15, row = (l>>4)*4 + reg
  if (which == 2) {
    // Vt[((b*16+h)*64+d)*2048 + t]; m = b*2048+t, col = h*64+d
#pragma unroll
    for (int ni = 0; ni < 4; ++ni) {
      int col = n0 + wc * 64 + ni * 16 + c16;
      int hh = col >> 6, dd = col & 63;
#pragma unroll
      for (int mi = 0; mi < 4; ++mi) {
        int m = m0 + wr * 64 + mi * 16 + g * 4;
        int bb = m >> 11, tt = m & 2047;
        u16x4 o;
#pragma unroll
        for (int r = 0; r < 4; ++r) o[r] = f2bf(acc[mi][ni][r]);
        *(u16x4*)(VT + ((size_t)((bb * 16 + hh) * 64 + dd)) * 2048 + tt) = o;
      }
    }
  } else {
    const float* G = which ? kg : qg;
    const float* Bt = which ? kb : qb;
    const float osc = which ? sK : sQ;
    u16* Ob = which ? KBB : QBB;
#pragma unroll
    for (int mi = 0; mi < 4; ++mi) {
      float sum[4], sq[4];
#pragma unroll
      for (int r = 0; r < 4; ++r) {
        float s = 0.f, q = 0.f;
#pragma unroll
        for (int ni = 0; ni < 4; ++ni) {
          float v = acc[mi][ni][r];
          s += v;
          q += v * v;
        }
#pragma unroll
        for (int msk = 1; msk < 16; msk <<= 1) {
          s += __shfl_xor(s, msk);
          q += __shfl_xor(q, msk);
        }
        sum[r] = s;
        sq[r] = q;
      }
#pragma unroll
      for (int ni = 0; ni < 4; ++ni) {
        int dloc = ni * 16 + c16;  // head-local (n0, wc*64 are 64-aligned)
        int colg = n0 + wc * 64 + ni * 16 + c16;
        float gv = G[dloc], bv = Bt[dloc];
#pragma unroll
        for (int r = 0; r < 4; ++r) {
          float mean = sum[r] * (1.f / 64.f);
          float var = sq[r] * (1.f / 64.f) - mean * mean;
          float y = (acc[mi][ni][r] - mean) * rsqrtf(var + 1e-5f) * gv + bv;
          int row = m0 + wr * 64 + mi * 16 + g * 4 + r;
          int orow = which ? row : (((row >> 11) << 10) | (row & 1023));
          Ob[(size_t)orow * N + colg] = f2bf(y * osc);
        }
      }
    }
  }
}

// ---------------- final GEMM: out = AO * Wu^T + bu, 64x128 tile ----------------
// Same chunk layout + 3-buffer counted-vmcnt (3 GLDS per wave per batch).

__global__ __launch_bounds__(256)
void gemm_u64(const u16* __restrict__ A, const u16* __restrict__ Bw,
              float* __restrict__ Of, const float* __restrict__ bias) {
  const int K = 1024, N = 1024;
  __shared__ alignas(16) u16 lAm[3][64 * 32];   // 12 KB
  __shared__ alignas(16) u16 lBm[3][128 * 32];  // 24 KB
  const int tid = threadIdx.x;
  const int wv = tid >> 6, l = tid & 63, g = l >> 4, c16 = l & 15;
  const int wr = wv >> 1, wc = wv & 1;
  const int m0 = blockIdx.x << 6, n0 = blockIdx.y << 7;

  f32x4 acc[2][4];
  const f32x4 z4 = {0.f, 0.f, 0.f, 0.f};
#pragma unroll
  for (int i = 0; i < 2; ++i)
#pragma unroll
    for (int j = 0; j < 4; ++j) acc[i][j] = z4;

  const u16* aSrc = A + (size_t)(m0 + l) * K + wv * 8;
  const u16* bSrc = Bw + (size_t)(n0 + l) * K + wv * 8;
  char* ldA = (char*)lAm;
  char* ldB = (char*)lBm;

#define STAGE_U(bi, kof)                                   \
  {                                                        \
    char* dA = ldA + (bi)*4096 + wv * 1024;                \
    char* dB = ldB + (bi)*8192 + wv * 2048;                \
    GLDS(aSrc + (kof), dA);                                \
    GLDS(bSrc + (kof), dB);                                \
    GLDS(bSrc + (size_t)64 * K + (kof), dB + 1024);        \
  }

  STAGE_U(0, 0);
  STAGE_U(1, 32);
  int cb = 0, sb = 2;
  for (int kt = 0; kt < 32; ++kt) {
    if (kt < 31) {
      asm volatile("s_waitcnt vmcnt(3)" ::: "memory");
    } else {
      asm volatile("s_waitcnt vmcnt(0)" ::: "memory");
    }
    __builtin_amdgcn_s_barrier();
    if (kt + 2 < 32) STAGE_U(sb, (kt + 2) << 5);
    const char* bA = ldA + cb * 4096;
    const char* bB = ldB + cb * 8192;
    bf16x8 af[2], bfr[4];
#pragma unroll
    for (int mi = 0; mi < 2; ++mi)
      af[mi] = *(const bf16x8*)(bA + g * 1024 + (wr * 32 + mi * 16 + c16) * 16);
#pragma unroll
    for (int ni = 0; ni < 4; ++ni)
      bfr[ni] = *(const bf16x8*)(bB + g * 2048 + (wc * 64 + ni * 16 + c16) * 16);
    __builtin_amdgcn_s_setprio(1);
#pragma unroll
    for (int mi = 0; mi < 2; ++mi)
#pragma unroll
      for (int ni = 0; ni < 4; ++ni)
        acc[mi][ni] = mfma16(af[mi], bfr[ni], acc[mi][ni]);
    __builtin_amdgcn_s_setprio(0);
    cb = cb == 2 ? 0 : cb + 1;
    sb = sb == 2 ? 0 : sb + 1;
  }
#undef STAGE_U

#pragma unroll
  for (int ni = 0; ni < 4; ++ni) {
    int col = n0 + wc * 64 + ni * 16 + c16;
    float bv = bias[col];
#pragma unroll
    for (int mi = 0; mi < 2; ++mi) {
      int row = m0 + wr * 32 + mi * 16 + g * 4;
      float* dst = Of + (size_t)row * N + col;
#pragma unroll
      for (int r = 0; r < 4; ++r) dst[(size_t)r * N] = acc[mi][ni][r] + bv;
    }
  }
}

// ---------------- flash attention, 32x32 MFMA, in-block KV-split ----------------
// grid (16, 4, 8) = (h, b, qt): qt is SLOWEST so the 8 qt-blocks of one (b,h)
// get linear ids differing by 64 (≡ 0 mod 8) -> same XCD -> shared L2 KV reads.
// block = 512 thr = 8 waves; w4 = wv&3 owns q-rows; kvh2 = wv>>2 = KV parity.
// Combine buffer aliases K/V tiles (union) -> LDS 64 KB -> 2 blocks/CU.

__global__ __launch_bounds__(512, 4)
void attn_kernel(const u16* __restrict__ Q, const u16* __restrict__ Kb,
                 const u16* __restrict__ Vt, u16* __restrict__ AO) {
  __shared__ union alignas(16) {
    struct { u16 K[2][2][4096]; u16 V[2][2][4096]; } kv;  // [kvh2][buf], 64 KB
    float cmb[4][64][34];                                 // used only after the loop
  } sm;
  const int tid = threadIdx.x;
  const int wv = tid >> 6, l = tid & 63;
  const int w4 = wv & 3, kvh2 = wv >> 2;
  const int lq = l & 31, hi = l >> 5;
  const int h = blockIdx.x, b = blockIdx.y, qt = blockIdx.z;
  const int qrow = (b << 10) + (qt << 7) + (w4 << 5) + lq;

  // Q fragments (B-operand): qf[kk] holds d = 16*kk + 8*hi + j, q-row = lq
  const u16* qp = Q + (size_t)qrow * 1024 + h * 64 + hi * 8;
  bf16x8 qf[4];
#pragma unroll
  for (int kk = 0; kk < 4; ++kk) qf[kk] = *(const bf16x8*)(qp + 16 * kk);

  f32x16 acc[2];
#pragma unroll
  for (int d0 = 0; d0 < 2; ++d0)
#pragma unroll
    for (int i = 0; i < 16; ++i) acc[d0][i] = 0.f;
  float m_run = -1e30f, l_run = 0.f;

  // staging sources: K chunk(dc=w4, kv=l), V chunk(kvc=w4, d=l); each parity its own tiles
  const u16* Ksrc = Kb + ((size_t)(b * 2048) + l) * 1024 + h * 64 + w4 * 8;
  const u16* Vsrc = Vt + ((size_t)((b * 16 + h) * 64) + l) * 2048 + w4 * 8;

#define STAGE_KV(bi, it)                                    \
  {                                                         \
    const int kv0 = ((it) << 7) + (kvh2 << 6);              \
    char* dK = (char*)sm.kv.K[kvh2][bi] + w4 * 1024;        \
    char* dV = (char*)sm.kv.V[kvh2][bi] + w4 * 1024;        \
    const u16* ks = Ksrc + (size_t)kv0 * 1024;              \
    const u16* vs = Vsrc + kv0;                             \
    GLDS(ks, dK);                                           \
    GLDS(ks + 32, dK + 4096);                               \
    GLDS(vs, dV);                                           \
    GLDS(vs + 32, dV + 4096);                               \
  }

  STAGE_KV(0, 0);
  __syncthreads();
  int buf = 0;

  for (int it = 0; it < 16; ++it) {
    if (it + 1 < 16) STAGE_KV(buf ^ 1, it + 1);
    const char* bK = (const char*)sm.kv.K[kvh2][buf];
    const char* bV = (const char*)sm.kv.V[kvh2][buf];

    // ---- QK^T ----
    f32x16 s[2];
#pragma unroll
    for (int kvh = 0; kvh < 2; ++kvh)
#pragma unroll
      for (int i = 0; i < 16; ++i) s[kvh][i] = 0.f;
    __builtin_amdgcn_s_setprio(1);
#pragma unroll
    for (int kk = 0; kk < 4; ++kk) {
      const char* kbase = bK + (2 * kk + hi) * 1024;
      bf16x8 kf0 = *(const bf16x8*)(kbase + lq * 16);
      bf16x8 kf1 = *(const bf16x8*)(kbase + (32 + lq) * 16);
      s[0] = mfma32(kf0, qf[kk], s[0]);
      s[1] = mfma32(kf1, qf[kk], s[1]);
    }
    __builtin_amdgcn_s_setprio(0);

    // ---- online softmax (exp2 domain), defer-max THR=8, 4-way-ILP trees ----
    float tm0 = fmaxf(s[0][0], s[1][0]), tm1 = fmaxf(s[0][1], s[1][1]);
    float tm2 = fmaxf(s[0][2], s[1][2]), tm3 = fmaxf(s[0][3], s[1][3]);
#pragma unroll
    for (int i = 4; i < 16; i += 4) {
      tm0 = fmaxf(tm0, fmaxf(s[0][i], s[1][i]));
      tm1 = fmaxf(tm1, fmaxf(s[0][i + 1], s[1][i + 1]));
      tm2 = fmaxf(tm2, fmaxf(s[0][i + 2], s[1][i + 2]));
      tm3 = fmaxf(tm3, fmaxf(s[0][i + 3], s[1][i + 3]));
    }
    float tm = fmaxf(fmaxf(tm0, tm1), fmaxf(tm2, tm3));
    tm = fmaxf(tm, __shfl_xor(tm, 32));
    if (!__all(tm <= m_run + 8.f)) {
      float mnew = fmaxf(m_run, tm);
      float corr = __builtin_amdgcn_exp2f(m_run - mnew);
      l_run *= corr;
#pragma unroll
      for (int d0 = 0; d0 < 2; ++d0)
#pragma unroll
        for (int i = 0; i < 16; ++i) acc[d0][i] *= corr;
      m_run = mnew;
    }
    float ts0 = 0.f, ts1 = 0.f, ts2 = 0.f, ts3 = 0.f;
#pragma unroll
    for (int kvh = 0; kvh < 2; ++kvh)
#pragma unroll
      for (int i = 0; i < 16; i += 4) {
        float p0 = __builtin_amdgcn_exp2f(s[kvh][i] - m_run);
        float p1 = __builtin_amdgcn_exp2f(s[kvh][i + 1] - m_run);
        float p2 = __builtin_amdgcn_exp2f(s[kvh][i + 2] - m_run);
        float p3 = __builtin_amdgcn_exp2f(s[kvh][i + 3] - m_run);
        s[kvh][i] = p0; s[kvh][i + 1] = p1; s[kvh][i + 2] = p2; s[kvh][i + 3] = p3;
        ts0 += p0; ts1 += p1; ts2 += p2; ts3 += p3;
      }
    float ts = (ts0 + ts1) + (ts2 + ts3);
    ts += __shfl_xor(ts, 32);
    l_run += ts;

    // ---- pack P -> bf16 pairs (1 VOP3 each): pk[kvh][kp][tt], kv_local = 8*kp+4*hi+2*tt
    unsigned int pk[2][4][2];
#pragma unroll
    for (int kvh = 0; kvh < 2; ++kvh)
#pragma unroll
      for (int kp = 0; kp < 4; ++kp)
#pragma unroll
        for (int tt = 0; tt < 2; ++tt)
          pk[kvh][kp][tt] = cvt_pk_bf16(s[kvh][4 * kp + 2 * tt], s[kvh][4 * kp + 2 * tt + 1]);

    // ---- PV: per kk build B-frag (P^T) via shfl_xor(32), then 2 mfma ----
    __builtin_amdgcn_s_setprio(1);
#pragma unroll
    for (int kk = 0; kk < 4; ++kk) {
      const int kvh = kk >> 1, kb = kk & 1;
      union { unsigned w[4]; bf16x8 v; } bw;
#pragma unroll
      for (int tt = 0; tt < 2; ++tt) {
        unsigned A0 = pk[kvh][2 * kb][tt];
        unsigned A1 = pk[kvh][2 * kb + 1][tt];
        unsigned S = (unsigned)__shfl_xor((int)(hi ? A0 : A1), 32);
        bw.w[tt] = hi ? S : A0;
        bw.w[2 + tt] = hi ? A1 : S;
      }
      const char* vbase = bV + (2 * kk + hi) * 1024;
      bf16x8 vf0 = *(const bf16x8*)(vbase + lq * 16);
      bf16x8 vf1 = *(const bf16x8*)(vbase + (32 + lq) * 16);
      acc[0] = mfma32(vf0, bw.v, acc[0]);
      acc[1] = mfma32(vf1, bw.v, acc[1]);
    }
    __builtin_amdgcn_s_setprio(0);
    __syncthreads();
    buf ^= 1;
  }
#undef STAGE_KV

  // ---- merge the two KV halves (exact flash combine) through aliased LDS ----
  if (wv >= 4) {
    float* cp = sm.cmb[w4][l];
#pragma unroll
    for (int d0 = 0; d0 < 2; ++d0)
#pragma unroll
      for (int i = 0; i < 16; ++i) cp[d0 * 16 + i] = acc[d0][i];
    cp[32] = m_run;
    cp[33] = l_run;
  }
  __syncthreads();
  if (wv < 4) {
    const float* cp = sm.cmb[w4][l];
    float m1 = cp[32], l1 = cp[33];
    float mm = fmaxf(m_run, m1);
    float c0 = __builtin_amdgcn_exp2f(m_run - mm);
    float c1 = __builtin_amdgcn_exp2f(m1 - mm);
    float invl = 1.f / (l_run * c0 + l1 * c1);
    float s0 = c0 * invl, s1 = c1 * invl;
    // O^T regs -> AO[q][h*64+d], d = 32*d0 + 8*rg + 4*hi + rr
#pragma unroll
    for (int d0 = 0; d0 < 2; ++d0)
#pragma unroll
      for (int rg = 0; rg < 4; ++rg) {
        float v0 = acc[d0][4 * rg + 0] * s0 + cp[d0 * 16 + 4 * rg + 0] * s1;
        float v1 = acc[d0][4 * rg + 1] * s0 + cp[d0 * 16 + 4 * rg + 1] * s1;
        float v2 = acc[d0][4 * rg + 2] * s0 + cp[d0 * 16 + 4 * rg + 2] * s1;
        float v3 = acc[d0][4 * rg + 3] * s0 + cp[d0 * 16 + 4 * rg + 3] * s1;
        u32x2 o;
        o.x = cvt_pk_bf16(v0, v1);
        o.y = cvt_pk_bf16(v2, v3);
        int d = 32 * d0 + 8 * rg + 4 * hi;
        *(u32x2*)(AO + (size_t)qrow * 1024 + h * 64 + d) = o;
      }
  }
}

// ---------------- launch ----------------

extern "C" void kernel_launch(void* const* d_in, const int* in_sizes, int n_in,
                              void* d_out, int out_size, void* d_ws, size_t ws_size,
                              hipStream_t stream) {
  const float* x = (const float*)d_in[0];
  const float* ctx = (const float*)d_in[1];
  const float* Wq = (const float*)d_in[2];
  const float* Wk = (const float*)d_in[3];
  const float* Wv = (const float*)d_in[4];
  const float* Wu = (const float*)d_in[5];
  const float* bu = (const float*)d_in[6];
  const float* qg = (const float*)d_in[7];
  const float* qb = (const float*)d_in[8];
  const float* kg = (const float*)d_in[9];
  const float* kb = (const float*)d_in[10];
  float* out = (float*)d_out;

  char* w = (char*)d_ws;
  u16* XCB = (u16*)(w);                       // 16 MB: xc bf16 [B,T,E]
  u16* WQB = (u16*)(w + ((size_t)16 << 20));  // 8 MB: Wq,Wk,Wv,Wu bf16 contiguous
  u16* QBB = (u16*)(w + ((size_t)24 << 20));  // 8 MB
  u16* KBB = (u16*)(w + ((size_t)32 << 20));  // 16 MB
  u16* VT = (u16*)(w + ((size_t)48 << 20));   // 16 MB
  u16* AO = (u16*)(w + ((size_t)64 << 20));   // 8 MB  (total 72 MB)

  const float invs = 0.17677669529663687f;          // 1024^-0.25
  const float invs_l2e = invs * 1.44269504088896f;  // fold log2(e) into Q for exp2 softmax

  cast_concat<<<2048, 256, 0, stream>>>(x, ctx, XCB);
  cast_w<<<1024, 256, 0, stream>>>(Wq, Wk, Wv, Wu, WQB);

  gemm_qkv<<<dim3(64, 24), 256, 0, stream>>>(XCB, WQB, QBB, KBB, VT,
                                             qg, qb, kg, kb, invs_l2e, invs);

  attn_kernel<<<dim3(16, 4, 8), 512, 0, stream>>>(QBB, KBB, VT, AO);

  gemm_u64<<<dim3(64, 8), 256, 0, stream>>>(AO, WQB + ((size_t)3 << 20), out, bu);
}

// Round 6
// 264.975 us; speedup vs baseline: 1.1139x; 1.1139x over previous
//
#include <hip/hip_runtime.h>
#include <cstdint>

// ContextualAttention on MI355X (gfx950), all-bf16 MFMA pipeline.
// R6: GEMMs back to R4's coalesced 2-phase dbuf structure with CORRECTED LDS
//     XOR swizzle ((row>>1)&3 instead of row&3): 4-way read conflict -> 2-way
//     (free), while keeping 64B-coalesced global staging. attn unchanged (R5).

typedef unsigned short u16;
typedef __attribute__((ext_vector_type(8))) short bf16x8;
typedef __attribute__((ext_vector_type(4))) float f32x4;
typedef __attribute__((ext_vector_type(16))) float f32x16;
typedef __attribute__((ext_vector_type(4))) unsigned short u16x4;
typedef __attribute__((ext_vector_type(2))) unsigned int u32x2;

#define GLDS(gsrc, ldst)                                                              \
  __builtin_amdgcn_global_load_lds(                                                   \
      (const __attribute__((address_space(1))) unsigned int*)(gsrc),                  \
      (__attribute__((address_space(3))) unsigned int*)(ldst), 16, 0, 0)

__device__ __forceinline__ u16 f2bf(float x) {
  unsigned int u = __float_as_uint(x);
  u += 0x7fffu + ((u >> 16) & 1u);
  return (u16)(u >> 16);
}

// packed f32x2 -> bf16x2 (RNE), single VOP3 (T12 recipe; no builtin on gfx950)
__device__ __forceinline__ unsigned cvt_pk_bf16(float lo, float hi) {
  unsigned r;
  asm("v_cvt_pk_bf16_f32 %0, %1, %2" : "=v"(r) : "v"(lo), "v"(hi));
  return r;
}

__device__ __forceinline__ f32x4 mfma16(bf16x8 a, bf16x8 b, f32x4 c) {
  return __builtin_amdgcn_mfma_f32_16x16x32_bf16(a, b, c, 0, 0, 0);
}
__device__ __forceinline__ f32x16 mfma32(bf16x8 a, bf16x8 b, f32x16 c) {
  return __builtin_amdgcn_mfma_f32_32x32x16_bf16(a, b, c, 0, 0, 0);
}

// ---------------- cast kernels ----------------

__global__ __launch_bounds__(256) void cast_concat(const float* __restrict__ x,
                                                   const float* __restrict__ c,
                                                   u16* __restrict__ o) {
  const int n4 = (8 << 20) / 4;  // B*T*E / 4
  for (int i = blockIdx.x * blockDim.x + threadIdx.x; i < n4; i += gridDim.x * blockDim.x) {
    int elem = i * 4;
    int b = elem >> 21;
    int rem = elem & ((1 << 21) - 1);
    int r = rem >> 10;
    int e = rem & 1023;
    const float* src = (r < 1024) ? (x + ((((size_t)(b << 10)) + r) << 10) + e)
                                  : (c + ((((size_t)(b << 10)) + (r - 1024)) << 10) + e);
    float4 v = *(const float4*)src;
    u16x4 ov;
    ov.x = f2bf(v.x); ov.y = f2bf(v.y); ov.z = f2bf(v.z); ov.w = f2bf(v.w);
    *(u16x4*)(o + elem) = ov;
  }
}

__global__ __launch_bounds__(256) void cast_w(const float* __restrict__ w0,
                                              const float* __restrict__ w1,
                                              const float* __restrict__ w2,
                                              const float* __restrict__ w3,
                                              u16* __restrict__ o) {
  const int n4 = (4 << 20) / 4;
  for (int i = blockIdx.x * blockDim.x + threadIdx.x; i < n4; i += gridDim.x * blockDim.x) {
    int elem = i * 4;
    int sel = elem >> 20;
    int loc = elem & ((1 << 20) - 1);
    const float* s = (sel == 0) ? w0 : (sel == 1) ? w1 : (sel == 2) ? w2 : w3;
    float4 v = *(const float4*)(s + loc);
    u16x4 ov;
    ov.x = f2bf(v.x); ov.y = f2bf(v.y); ov.z = f2bf(v.z); ov.w = f2bf(v.w);
    *(u16x4*)(o + elem) = ov;
  }
}

// ---------------- merged QKV GEMM: 128x128 tile, BK=32, 2-phase dbuf ----------------
// LDS rows of 64B; read slot = g ^ ((row>>1)&3)  (2-way max = conflict-free);
// staging keeps 64B global coalescing with pre-swizzled chunk (tid&3)^((srow>>1)&3).
// grid (64, 24). ny>>3: 0=Q (LN epi, compacted rows), 1=K (LN epi), 2=V (transposed).

__global__ __launch_bounds__(256)
void gemm_qkv(const u16* __restrict__ XCB, const u16* __restrict__ Wall,
              u16* __restrict__ QBB, u16* __restrict__ KBB, u16* __restrict__ VT,
              const float* __restrict__ qg, const float* __restrict__ qb,
              const float* __restrict__ kg, const float* __restrict__ kb,
              float sQ, float sK) {
  const int ny = blockIdx.y;
  const int which = ny >> 3;
  const int m0 = blockIdx.x << 7;
  if (which == 0 && (m0 & 2047) >= 1024) return;  // Q only from x rows
  const int n0 = (ny & 7) << 7;
  const u16* Bw = Wall + ((size_t)which << 20);
  const int K = 1024, N = 1024;

  __shared__ alignas(16) u16 lA[2][128 * 32];
  __shared__ alignas(16) u16 lB[2][128 * 32];
  const int tid = threadIdx.x;
  const int wv = tid >> 6, l = tid & 63, g = l >> 4, c16 = l & 15;
  const int wr = wv >> 1, wc = wv & 1;

  f32x4 acc[4][4];
  const f32x4 z4 = {0.f, 0.f, 0.f, 0.f};
#pragma unroll
  for (int i = 0; i < 4; ++i)
#pragma unroll
    for (int j = 0; j < 4; ++j) acc[i][j] = z4;

  // staging: 16B chunks, linear LDS dest (byte = tid*16), pre-swizzled global chunk
  const int srow = tid >> 2;
  const int scA = (tid & 3) ^ ((srow >> 1) & 3);
  const u16* aSrc = XCB + (size_t)(m0 + srow) * K + scA * 8;
  const u16* bSrc = Bw + (size_t)(n0 + srow) * K + scA * 8;
  char* ldA = (char*)lA;
  char* ldB = (char*)lB;
  const int lof = wv * 1024;

#define STAGE_G(bi, kof)                                   \
  {                                                        \
    char* dA = ldA + (bi)*8192 + lof;                      \
    char* dB = ldB + (bi)*8192 + lof;                      \
    GLDS(aSrc + (kof), dA);                                \
    GLDS(aSrc + (size_t)64 * K + (kof), dA + 4096);        \
    GLDS(bSrc + (kof), dB);                                \
    GLDS(bSrc + (size_t)64 * K + (kof), dB + 4096);        \
  }

  STAGE_G(0, 0);
  __syncthreads();
  int buf = 0;
  for (int kt = 0; kt < 32; ++kt) {
    if (kt + 1 < 32) STAGE_G(buf ^ 1, (kt + 1) << 5);
    const char* bA = ldA + buf * 8192;
    const char* bB = ldB + buf * 8192;
    bf16x8 af[4], bfr[4];
#pragma unroll
    for (int mi = 0; mi < 4; ++mi) {
      int row = wr * 64 + mi * 16 + c16;
      af[mi] = *(const bf16x8*)(bA + row * 64 + ((g * 16) ^ (((row >> 1) & 3) << 4)));
    }
#pragma unroll
    for (int ni = 0; ni < 4; ++ni) {
      int row = wc * 64 + ni * 16 + c16;
      bfr[ni] = *(const bf16x8*)(bB + row * 64 + ((g * 16) ^ (((row >> 1) & 3) << 4)));
    }
    __builtin_amdgcn_s_setprio(1);
#pragma unroll
    for (int mi = 0; mi < 4; ++mi)
#pragma unroll
      for (int ni = 0; ni < 4; ++ni)
        acc[mi][ni] = mfma16(af[mi], bfr[ni], acc[mi][ni]);
    __builtin_amdgcn_s_setprio(0);
    __syncthreads();
    buf ^= 1;
  }
#undef STAGE_G

  // ---- epilogues ----  C layout: col = l&15, row = (l>>4)*4 + reg
  if (which == 2) {
    // Vt[((b*16+h)*64+d)*2048 + t]; m = b*2048+t, col = h*64+d
#pragma unroll
    for (int ni = 0; ni < 4; ++ni) {
      int col = n0 + wc * 64 + ni * 16 + c16;
      int hh = col >> 6, dd = col & 63;
#pragma unroll
      for (int mi = 0; mi < 4; ++mi) {
        int m = m0 + wr * 64 + mi * 16 + g * 4;
        int bb = m >> 11, tt = m & 2047;
        u16x4 o;
#pragma unroll
        for (int r = 0; r < 4; ++r) o[r] = f2bf(acc[mi][ni][r]);
        *(u16x4*)(VT + ((size_t)((bb * 16 + hh) * 64 + dd)) * 2048 + tt) = o;
      }
    }
  } else {
    const float* G = which ? kg : qg;
    const float* Bt = which ? kb : qb;
    const float osc = which ? sK : sQ;
    u16* Ob = which ? KBB : QBB;
#pragma unroll
    for (int mi = 0; mi < 4; ++mi) {
      float sum[4], sq[4];
#pragma unroll
      for (int r = 0; r < 4; ++r) {
        float s = 0.f, q = 0.f;
#pragma unroll
        for (int ni = 0; ni < 4; ++ni) {
          float v = acc[mi][ni][r];
          s += v;
          q += v * v;
        }
#pragma unroll
        for (int msk = 1; msk < 16; msk <<= 1) {
          s += __shfl_xor(s, msk);
          q += __shfl_xor(q, msk);
        }
        sum[r] = s;
        sq[r] = q;
      }
#pragma unroll
      for (int ni = 0; ni < 4; ++ni) {
        int dloc = ni * 16 + c16;  // head-local (n0, wc*64 are 64-aligned)
        int colg = n0 + wc * 64 + ni * 16 + c16;
        float gv = G[dloc], bv = Bt[dloc];
#pragma unroll
        for (int r = 0; r < 4; ++r) {
          float mean = sum[r] * (1.f / 64.f);
          float var = sq[r] * (1.f / 64.f) - mean * mean;
          float y = (acc[mi][ni][r] - mean) * rsqrtf(var + 1e-5f) * gv + bv;
          int row = m0 + wr * 64 + mi * 16 + g * 4 + r;
          int orow = which ? row : (((row >> 11) << 10) | (row & 1023));
          Ob[(size_t)orow * N + colg] = f2bf(y * osc);
        }
      }
    }
  }
}

// ---------------- final GEMM: out = AO * Wu^T + bu, 64x128 tile, 2-phase dbuf ----------------

__global__ __launch_bounds__(256)
void gemm_u64(const u16* __restrict__ A, const u16* __restrict__ Bw,
              float* __restrict__ Of, const float* __restrict__ bias) {
  const int K = 1024, N = 1024;
  __shared__ alignas(16) u16 lA[2][64 * 32];
  __shared__ alignas(16) u16 lB[2][128 * 32];
  const int tid = threadIdx.x;
  const int wv = tid >> 6, l = tid & 63, g = l >> 4, c16 = l & 15;
  const int wr = wv >> 1, wc = wv & 1;
  const int m0 = blockIdx.x << 6, n0 = blockIdx.y << 7;

  f32x4 acc[2][4];
  const f32x4 z4 = {0.f, 0.f, 0.f, 0.f};
#pragma unroll
  for (int i = 0; i < 2; ++i)
#pragma unroll
    for (int j = 0; j < 4; ++j) acc[i][j] = z4;

  const int srow = tid >> 2;
  const int sc = (tid & 3) ^ ((srow >> 1) & 3);
  const u16* aSrc = A + (size_t)(m0 + srow) * K + sc * 8;  // srow < 64
  const u16* bSrc = Bw + (size_t)(n0 + srow) * K + sc * 8;
  char* ldA = (char*)lA;
  char* ldB = (char*)lB;
  const int lof = wv * 1024;

#define STAGE_U(bi, kof)                                   \
  {                                                        \
    char* dA = ldA + (bi)*4096 + lof;                      \
    char* dB = ldB + (bi)*8192 + lof;                      \
    GLDS(aSrc + (kof), dA);                                \
    GLDS(bSrc + (kof), dB);                                \
    GLDS(bSrc + (size_t)64 * K + (kof), dB + 4096);        \
  }

  STAGE_U(0, 0);
  __syncthreads();
  int buf = 0;
  for (int kt = 0; kt < 32; ++kt) {
    if (kt + 1 < 32) STAGE_U(buf ^ 1, (kt + 1) << 5);
    const char* bA = ldA + buf * 4096;
    const char* bB = ldB + buf * 8192;
    bf16x8 af[2], bfr[4];
#pragma unroll
    for (int mi = 0; mi < 2; ++mi) {
      int row = wr * 32 + mi * 16 + c16;
      af[mi] = *(const bf16x8*)(bA + row * 64 + ((g * 16) ^ (((row >> 1) & 3) << 4)));
    }
#pragma unroll
    for (int ni = 0; ni < 4; ++ni) {
      int row = wc * 64 + ni * 16 + c16;
      bfr[ni] = *(const bf16x8*)(bB + row * 64 + ((g * 16) ^ (((row >> 1) & 3) << 4)));
    }
    __builtin_amdgcn_s_setprio(1);
#pragma unroll
    for (int mi = 0; mi < 2; ++mi)
#pragma unroll
      for (int ni = 0; ni < 4; ++ni)
        acc[mi][ni] = mfma16(af[mi], bfr[ni], acc[mi][ni]);
    __builtin_amdgcn_s_setprio(0);
    __syncthreads();
    buf ^= 1;
  }
#undef STAGE_U

#pragma unroll
  for (int ni = 0; ni < 4; ++ni) {
    int col = n0 + wc * 64 + ni * 16 + c16;
    float bv = bias[col];
#pragma unroll
    for (int mi = 0; mi < 2; ++mi) {
      int row = m0 + wr * 32 + mi * 16 + g * 4;
      float* dst = Of + (size_t)row * N + col;
#pragma unroll
      for (int r = 0; r < 4; ++r) dst[(size_t)r * N] = acc[mi][ni][r] + bv;
    }
  }
}

// ---------------- flash attention, 32x32 MFMA, in-block KV-split ----------------
// grid (16, 4, 8) = (h, b, qt): qt SLOWEST -> the 8 qt-blocks of one (b,h) land on
// one XCD (linear ids differ by 64 ≡ 0 mod 8) and share L2-resident K/V.
// block = 512 thr = 8 waves; w4 = wv&3 owns q-rows; kvh2 = wv>>2 = KV parity.
// Combine buffer aliases K/V tiles (union) -> LDS 64 KB -> 2 blocks/CU.

__global__ __launch_bounds__(512, 4)
void attn_kernel(const u16* __restrict__ Q, const u16* __restrict__ Kb,
                 const u16* __restrict__ Vt, u16* __restrict__ AO) {
  __shared__ union alignas(16) {
    struct { u16 K[2][2][4096]; u16 V[2][2][4096]; } kv;  // [kvh2][buf], 64 KB
    float cmb[4][64][34];                                 // used only after the loop
  } sm;
  const int tid = threadIdx.x;
  const int wv = tid >> 6, l = tid & 63;
  const int w4 = wv & 3, kvh2 = wv >> 2;
  const int lq = l & 31, hi = l >> 5;
  const int h = blockIdx.x, b = blockIdx.y, qt = blockIdx.z;
  const int qrow = (b << 10) + (qt << 7) + (w4 << 5) + lq;

  // Q fragments (B-operand): qf[kk] holds d = 16*kk + 8*hi + j, q-row = lq
  const u16* qp = Q + (size_t)qrow * 1024 + h * 64 + hi * 8;
  bf16x8 qf[4];
#pragma unroll
  for (int kk = 0; kk < 4; ++kk) qf[kk] = *(const bf16x8*)(qp + 16 * kk);

  f32x16 acc[2];
#pragma unroll
  for (int d0 = 0; d0 < 2; ++d0)
#pragma unroll
    for (int i = 0; i < 16; ++i) acc[d0][i] = 0.f;
  float m_run = -1e30f, l_run = 0.f;

  // staging sources: K chunk(dc=w4, kv=l), V chunk(kvc=w4, d=l); each parity its own tiles
  const u16* Ksrc = Kb + ((size_t)(b * 2048) + l) * 1024 + h * 64 + w4 * 8;
  const u16* Vsrc = Vt + ((size_t)((b * 16 + h) * 64) + l) * 2048 + w4 * 8;

#define STAGE_KV(bi, it)                                    \
  {                                                         \
    const int kv0 = ((it) << 7) + (kvh2 << 6);              \
    char* dK = (char*)sm.kv.K[kvh2][bi] + w4 * 1024;        \
    char* dV = (char*)sm.kv.V[kvh2][bi] + w4 * 1024;        \
    const u16* ks = Ksrc + (size_t)kv0 * 1024;              \
    const u16* vs = Vsrc + kv0;                             \
    GLDS(ks, dK);                                           \
    GLDS(ks + 32, dK + 4096);                               \
    GLDS(vs, dV);                                           \
    GLDS(vs + 32, dV + 4096);                               \
  }

  STAGE_KV(0, 0);
  __syncthreads();
  int buf = 0;

  for (int it = 0; it < 16; ++it) {
    if (it + 1 < 16) STAGE_KV(buf ^ 1, it + 1);
    const char* bK = (const char*)sm.kv.K[kvh2][buf];
    const char* bV = (const char*)sm.kv.V[kvh2][buf];

    // ---- QK^T ----
    f32x16 s[2];
#pragma unroll
    for (int kvh = 0; kvh < 2; ++kvh)
#pragma unroll
      for (int i = 0; i < 16; ++i) s[kvh][i] = 0.f;
    __builtin_amdgcn_s_setprio(1);
#pragma unroll
    for (int kk = 0; kk < 4; ++kk) {
      const char* kbase = bK + (2 * kk + hi) * 1024;
      bf16x8 kf0 = *(const bf16x8*)(kbase + lq * 16);
      bf16x8 kf1 = *(const bf16x8*)(kbase + (32 + lq) * 16);
      s[0] = mfma32(kf0, qf[kk], s[0]);
      s[1] = mfma32(kf1, qf[kk], s[1]);
    }
    __builtin_amdgcn_s_setprio(0);

    // ---- online softmax (exp2 domain), defer-max THR=8, 4-way-ILP trees ----
    float tm0 = fmaxf(s[0][0], s[1][0]), tm1 = fmaxf(s[0][1], s[1][1]);
    float tm2 = fmaxf(s[0][2], s[1][2]), tm3 = fmaxf(s[0][3], s[1][3]);
#pragma unroll
    for (int i = 4; i < 16; i += 4) {
      tm0 = fmaxf(tm0, fmaxf(s[0][i], s[1][i]));
      tm1 = fmaxf(tm1, fmaxf(s[0][i + 1], s[1][i + 1]));
      tm2 = fmaxf(tm2, fmaxf(s[0][i + 2], s[1][i + 2]));
      tm3 = fmaxf(tm3, fmaxf(s[0][i + 3], s[1][i + 3]));
    }
    float tm = fmaxf(fmaxf(tm0, tm1), fmaxf(tm2, tm3));
    tm = fmaxf(tm, __shfl_xor(tm, 32));
    if (!__all(tm <= m_run + 8.f)) {
      float mnew = fmaxf(m_run, tm);
      float corr = __builtin_amdgcn_exp2f(m_run - mnew);
      l_run *= corr;
#pragma unroll
      for (int d0 = 0; d0 < 2; ++d0)
#pragma unroll
        for (int i = 0; i < 16; ++i) acc[d0][i] *= corr;
      m_run = mnew;
    }
    float ts0 = 0.f, ts1 = 0.f, ts2 = 0.f, ts3 = 0.f;
#pragma unroll
    for (int kvh = 0; kvh < 2; ++kvh)
#pragma unroll
      for (int i = 0; i < 16; i += 4) {
        float p0 = __builtin_amdgcn_exp2f(s[kvh][i] - m_run);
        float p1 = __builtin_amdgcn_exp2f(s[kvh][i + 1] - m_run);
        float p2 = __builtin_amdgcn_exp2f(s[kvh][i + 2] - m_run);
        float p3 = __builtin_amdgcn_exp2f(s[kvh][i + 3] - m_run);
        s[kvh][i] = p0; s[kvh][i + 1] = p1; s[kvh][i + 2] = p2; s[kvh][i + 3] = p3;
        ts0 += p0; ts1 += p1; ts2 += p2; ts3 += p3;
      }
    float ts = (ts0 + ts1) + (ts2 + ts3);
    ts += __shfl_xor(ts, 32);
    l_run += ts;

    // ---- pack P -> bf16 pairs (1 VOP3 each): pk[kvh][kp][tt], kv_local = 8*kp+4*hi+2*tt
    unsigned int pk[2][4][2];
#pragma unroll
    for (int kvh = 0; kvh < 2; ++kvh)
#pragma unroll
      for (int kp = 0; kp < 4; ++kp)
#pragma unroll
        for (int tt = 0; tt < 2; ++tt)
          pk[kvh][kp][tt] = cvt_pk_bf16(s[kvh][4 * kp + 2 * tt], s[kvh][4 * kp + 2 * tt + 1]);

    // ---- PV: per kk build B-frag (P^T) via shfl_xor(32), then 2 mfma ----
    __builtin_amdgcn_s_setprio(1);
#pragma unroll
    for (int kk = 0; kk < 4; ++kk) {
      const int kvh = kk >> 1, kb = kk & 1;
      union { unsigned w[4]; bf16x8 v; } bw;
#pragma unroll
      for (int tt = 0; tt < 2; ++tt) {
        unsigned A0 = pk[kvh][2 * kb][tt];
        unsigned A1 = pk[kvh][2 * kb + 1][tt];
        unsigned S = (unsigned)__shfl_xor((int)(hi ? A0 : A1), 32);
        bw.w[tt] = hi ? S : A0;
        bw.w[2 + tt] = hi ? A1 : S;
      }
      const char* vbase = bV + (2 * kk + hi) * 1024;
      bf16x8 vf0 = *(const bf16x8*)(vbase + lq * 16);
      bf16x8 vf1 = *(const bf16x8*)(vbase + (32 + lq) * 16);
      acc[0] = mfma32(vf0, bw.v, acc[0]);
      acc[1] = mfma32(vf1, bw.v, acc[1]);
    }
    __builtin_amdgcn_s_setprio(0);
    __syncthreads();
    buf ^= 1;
  }
#undef STAGE_KV

  // ---- merge the two KV halves (exact flash combine) through aliased LDS ----
  if (wv >= 4) {
    float* cp = sm.cmb[w4][l];
#pragma unroll
    for (int d0 = 0; d0 < 2; ++d0)
#pragma unroll
      for (int i = 0; i < 16; ++i) cp[d0 * 16 + i] = acc[d0][i];
    cp[32] = m_run;
    cp[33] = l_run;
  }
  __syncthreads();
  if (wv < 4) {
    const float* cp = sm.cmb[w4][l];
    float m1 = cp[32], l1 = cp[33];
    float mm = fmaxf(m_run, m1);
    float c0 = __builtin_amdgcn_exp2f(m_run - mm);
    float c1 = __builtin_amdgcn_exp2f(m1 - mm);
    float invl = 1.f / (l_run * c0 + l1 * c1);
    float s0 = c0 * invl, s1 = c1 * invl;
    // O^T regs -> AO[q][h*64+d], d = 32*d0 + 8*rg + 4*hi + rr
#pragma unroll
    for (int d0 = 0; d0 < 2; ++d0)
#pragma unroll
      for (int rg = 0; rg < 4; ++rg) {
        float v0 = acc[d0][4 * rg + 0] * s0 + cp[d0 * 16 + 4 * rg + 0] * s1;
        float v1 = acc[d0][4 * rg + 1] * s0 + cp[d0 * 16 + 4 * rg + 1] * s1;
        float v2 = acc[d0][4 * rg + 2] * s0 + cp[d0 * 16 + 4 * rg + 2] * s1;
        float v3 = acc[d0][4 * rg + 3] * s0 + cp[d0 * 16 + 4 * rg + 3] * s1;
        u32x2 o;
        o.x = cvt_pk_bf16(v0, v1);
        o.y = cvt_pk_bf16(v2, v3);
        int d = 32 * d0 + 8 * rg + 4 * hi;
        *(u32x2*)(AO + (size_t)qrow * 1024 + h * 64 + d) = o;
      }
  }
}

// ---------------- launch ----------------

extern "C" void kernel_launch(void* const* d_in, const int* in_sizes, int n_in,
                              void* d_out, int out_size, void* d_ws, size_t ws_size,
                              hipStream_t stream) {
  const float* x = (const float*)d_in[0];
  const float* ctx = (const float*)d_in[1];
  const float* Wq = (const float*)d_in[2];
  const float* Wk = (const float*)d_in[3];
  const float* Wv = (const float*)d_in[4];
  const float* Wu = (const float*)d_in[5];
  const float* bu = (const float*)d_in[6];
  const float* qg = (const float*)d_in[7];
  const float* qb = (const float*)d_in[8];
  const float* kg = (const float*)d_in[9];
  const float* kb = (const float*)d_in[10];
  float* out = (float*)d_out;

  char* w = (char*)d_ws;
  u16* XCB = (u16*)(w);                       // 16 MB: xc bf16 [B,T,E]
  u16* WQB = (u16*)(w + ((size_t)16 << 20));  // 8 MB: Wq,Wk,Wv,Wu bf16 contiguous
  u16* QBB = (u16*)(w + ((size_t)24 << 20));  // 8 MB
  u16* KBB = (u16*)(w + ((size_t)32 << 20));  // 16 MB
  u16* VT = (u16*)(w + ((size_t)48 << 20));   // 16 MB
  u16* AO = (u16*)(w + ((size_t)64 << 20));   // 8 MB  (total 72 MB)

  const float invs = 0.17677669529663687f;          // 1024^-0.25
  const float invs_l2e = invs * 1.44269504088896f;  // fold log2(e) into Q for exp2 softmax

  cast_concat<<<2048, 256, 0, stream>>>(x, ctx, XCB);
  cast_w<<<1024, 256, 0, stream>>>(Wq, Wk, Wv, Wu, WQB);

  gemm_qkv<<<dim3(64, 24), 256, 0, stream>>>(XCB, WQB, QBB, KBB, VT,
                                             qg, qb, kg, kb, invs_l2e, invs);

  attn_kernel<<<dim3(16, 4, 8), 512, 0, stream>>>(QBB, KBB, VT, AO);

  gemm_u64<<<dim3(64, 8), 256, 0, stream>>>(AO, WQB + ((size_t)3 << 20), out, bu);
}

// Round 7
// 260.976 us; speedup vs baseline: 1.1309x; 1.0153x over previous
//
#include <hip/hip_runtime.h>
#include <cstdint>

// ContextualAttention on MI355X (gfx950), all-bf16 MFMA pipeline.
// R7: GEMMs = counted-vmcnt 3-buffer pipeline (T4: vmcnt(4)->barrier->STAGE(t+2)
//     ->compute(t), never drain-0 in loop) + R6's coalesced staging and
//     conflict-free ((row>>1)&3) swizzle. 48KB LDS -> 3 blocks/CU. attn unchanged.

typedef unsigned short u16;
typedef __attribute__((ext_vector_type(8))) short bf16x8;
typedef __attribute__((ext_vector_type(4))) float f32x4;
typedef __attribute__((ext_vector_type(16))) float f32x16;
typedef __attribute__((ext_vector_type(4))) unsigned short u16x4;
typedef __attribute__((ext_vector_type(2))) unsigned int u32x2;

#define GLDS(gsrc, ldst)                                                              \
  __builtin_amdgcn_global_load_lds(                                                   \
      (const __attribute__((address_space(1))) unsigned int*)(gsrc),                  \
      (__attribute__((address_space(3))) unsigned int*)(ldst), 16, 0, 0)

__device__ __forceinline__ u16 f2bf(float x) {
  unsigned int u = __float_as_uint(x);
  u += 0x7fffu + ((u >> 16) & 1u);
  return (u16)(u >> 16);
}

// packed f32x2 -> bf16x2 (RNE), single VOP3 (T12 recipe; no builtin on gfx950)
__device__ __forceinline__ unsigned cvt_pk_bf16(float lo, float hi) {
  unsigned r;
  asm("v_cvt_pk_bf16_f32 %0, %1, %2" : "=v"(r) : "v"(lo), "v"(hi));
  return r;
}

__device__ __forceinline__ f32x4 mfma16(bf16x8 a, bf16x8 b, f32x4 c) {
  return __builtin_amdgcn_mfma_f32_16x16x32_bf16(a, b, c, 0, 0, 0);
}
__device__ __forceinline__ f32x16 mfma32(bf16x8 a, bf16x8 b, f32x16 c) {
  return __builtin_amdgcn_mfma_f32_32x32x16_bf16(a, b, c, 0, 0, 0);
}

// ---------------- cast kernels ----------------

__global__ __launch_bounds__(256) void cast_concat(const float* __restrict__ x,
                                                   const float* __restrict__ c,
                                                   u16* __restrict__ o) {
  const int n4 = (8 << 20) / 4;  // B*T*E / 4
  for (int i = blockIdx.x * blockDim.x + threadIdx.x; i < n4; i += gridDim.x * blockDim.x) {
    int elem = i * 4;
    int b = elem >> 21;
    int rem = elem & ((1 << 21) - 1);
    int r = rem >> 10;
    int e = rem & 1023;
    const float* src = (r < 1024) ? (x + ((((size_t)(b << 10)) + r) << 10) + e)
                                  : (c + ((((size_t)(b << 10)) + (r - 1024)) << 10) + e);
    float4 v = *(const float4*)src;
    u16x4 ov;
    ov.x = f2bf(v.x); ov.y = f2bf(v.y); ov.z = f2bf(v.z); ov.w = f2bf(v.w);
    *(u16x4*)(o + elem) = ov;
  }
}

__global__ __launch_bounds__(256) void cast_w(const float* __restrict__ w0,
                                              const float* __restrict__ w1,
                                              const float* __restrict__ w2,
                                              const float* __restrict__ w3,
                                              u16* __restrict__ o) {
  const int n4 = (4 << 20) / 4;
  for (int i = blockIdx.x * blockDim.x + threadIdx.x; i < n4; i += gridDim.x * blockDim.x) {
    int elem = i * 4;
    int sel = elem >> 20;
    int loc = elem & ((1 << 20) - 1);
    const float* s = (sel == 0) ? w0 : (sel == 1) ? w1 : (sel == 2) ? w2 : w3;
    float4 v = *(const float4*)(s + loc);
    u16x4 ov;
    ov.x = f2bf(v.x); ov.y = f2bf(v.y); ov.z = f2bf(v.z); ov.w = f2bf(v.w);
    *(u16x4*)(o + elem) = ov;
  }
}

// ---------------- merged QKV GEMM: 128x128 tile, BK=32, 3-buf counted vmcnt ----------------
// Coalesced staging (64B/quad-row), pre-swizzled chunk (tid&3)^((srow>>1)&3);
// read slot g ^ ((row>>1)&3) -> worst 2-way (free). Loop: vmcnt(4); barrier;
// STAGE(t+2); compute(t). Loads stay in flight across barriers (T4).
// grid (64, 24). ny>>3: 0=Q (LN epi, compacted rows), 1=K (LN epi), 2=V (transposed).

__global__ __launch_bounds__(256)
void gemm_qkv(const u16* __restrict__ XCB, const u16* __restrict__ Wall,
              u16* __restrict__ QBB, u16* __restrict__ KBB, u16* __restrict__ VT,
              const float* __restrict__ qg, const float* __restrict__ qb,
              const float* __restrict__ kg, const float* __restrict__ kb,
              float sQ, float sK) {
  const int ny = blockIdx.y;
  const int which = ny >> 3;
  const int m0 = blockIdx.x << 7;
  if (which == 0 && (m0 & 2047) >= 1024) return;  // Q only from x rows
  const int n0 = (ny & 7) << 7;
  const u16* Bw = Wall + ((size_t)which << 20);
  const int K = 1024, N = 1024;

  __shared__ alignas(16) u16 lA[3][128 * 32];  // 24 KB
  __shared__ alignas(16) u16 lB[3][128 * 32];  // 24 KB
  const int tid = threadIdx.x;
  const int wv = tid >> 6, l = tid & 63, g = l >> 4, c16 = l & 15;
  const int wr = wv >> 1, wc = wv & 1;

  f32x4 acc[4][4];
  const f32x4 z4 = {0.f, 0.f, 0.f, 0.f};
#pragma unroll
  for (int i = 0; i < 4; ++i)
#pragma unroll
    for (int j = 0; j < 4; ++j) acc[i][j] = z4;

  // staging: 16B chunks, linear LDS dest (byte = tid*16), pre-swizzled global chunk
  const int srow = tid >> 2;
  const int scA = (tid & 3) ^ ((srow >> 1) & 3);
  const u16* aSrc = XCB + (size_t)(m0 + srow) * K + scA * 8;
  const u16* bSrc = Bw + (size_t)(n0 + srow) * K + scA * 8;
  char* ldA = (char*)lA;
  char* ldB = (char*)lB;
  const int lof = wv * 1024;

#define STAGE_G(bi, kof)                                   \
  {                                                        \
    char* dA = ldA + (bi)*8192 + lof;                      \
    char* dB = ldB + (bi)*8192 + lof;                      \
    GLDS(aSrc + (kof), dA);                                \
    GLDS(aSrc + (size_t)64 * K + (kof), dA + 4096);        \
    GLDS(bSrc + (kof), dB);                                \
    GLDS(bSrc + (size_t)64 * K + (kof), dB + 4096);        \
  }

  STAGE_G(0, 0);
  STAGE_G(1, 32);
  int cb = 0, sb = 2;
  for (int kt = 0; kt < 32; ++kt) {
    if (kt < 31) {
      asm volatile("s_waitcnt vmcnt(4)" ::: "memory");
    } else {
      asm volatile("s_waitcnt vmcnt(0)" ::: "memory");
    }
    __builtin_amdgcn_s_barrier();
    if (kt + 2 < 32) STAGE_G(sb, (kt + 2) << 5);
    const char* bA = ldA + cb * 8192;
    const char* bB = ldB + cb * 8192;
    bf16x8 af[4], bfr[4];
#pragma unroll
    for (int mi = 0; mi < 4; ++mi) {
      int row = wr * 64 + mi * 16 + c16;
      af[mi] = *(const bf16x8*)(bA + row * 64 + ((g * 16) ^ (((row >> 1) & 3) << 4)));
    }
#pragma unroll
    for (int ni = 0; ni < 4; ++ni) {
      int row = wc * 64 + ni * 16 + c16;
      bfr[ni] = *(const bf16x8*)(bB + row * 64 + ((g * 16) ^ (((row >> 1) & 3) << 4)));
    }
    __builtin_amdgcn_s_setprio(1);
#pragma unroll
    for (int mi = 0; mi < 4; ++mi)
#pragma unroll
      for (int ni = 0; ni < 4; ++ni)
        acc[mi][ni] = mfma16(af[mi], bfr[ni], acc[mi][ni]);
    __builtin_amdgcn_s_setprio(0);
    cb = cb == 2 ? 0 : cb + 1;
    sb = sb == 2 ? 0 : sb + 1;
  }
#undef STAGE_G

  // ---- epilogues ----  C layout: col = l&15, row = (l>>4)*4 + reg
  if (which == 2) {
    // Vt[((b*16+h)*64+d)*2048 + t]; m = b*2048+t, col = h*64+d
#pragma unroll
    for (int ni = 0; ni < 4; ++ni) {
      int col = n0 + wc * 64 + ni * 16 + c16;
      int hh = col >> 6, dd = col & 63;
#pragma unroll
      for (int mi = 0; mi < 4; ++mi) {
        int m = m0 + wr * 64 + mi * 16 + g * 4;
        int bb = m >> 11, tt = m & 2047;
        u16x4 o;
#pragma unroll
        for (int r = 0; r < 4; ++r) o[r] = f2bf(acc[mi][ni][r]);
        *(u16x4*)(VT + ((size_t)((bb * 16 + hh) * 64 + dd)) * 2048 + tt) = o;
      }
    }
  } else {
    const float* G = which ? kg : qg;
    const float* Bt = which ? kb : qb;
    const float osc = which ? sK : sQ;
    u16* Ob = which ? KBB : QBB;
#pragma unroll
    for (int mi = 0; mi < 4; ++mi) {
      float sum[4], sq[4];
#pragma unroll
      for (int r = 0; r < 4; ++r) {
        float s = 0.f, q = 0.f;
#pragma unroll
        for (int ni = 0; ni < 4; ++ni) {
          float v = acc[mi][ni][r];
          s += v;
          q += v * v;
        }
#pragma unroll
        for (int msk = 1; msk < 16; msk <<= 1) {
          s += __shfl_xor(s, msk);
          q += __shfl_xor(q, msk);
        }
        sum[r] = s;
        sq[r] = q;
      }
#pragma unroll
      for (int ni = 0; ni < 4; ++ni) {
        int dloc = ni * 16 + c16;  // head-local (n0, wc*64 are 64-aligned)
        int colg = n0 + wc * 64 + ni * 16 + c16;
        float gv = G[dloc], bv = Bt[dloc];
#pragma unroll
        for (int r = 0; r < 4; ++r) {
          float mean = sum[r] * (1.f / 64.f);
          float var = sq[r] * (1.f / 64.f) - mean * mean;
          float y = (acc[mi][ni][r] - mean) * rsqrtf(var + 1e-5f) * gv + bv;
          int row = m0 + wr * 64 + mi * 16 + g * 4 + r;
          int orow = which ? row : (((row >> 11) << 10) | (row & 1023));
          Ob[(size_t)orow * N + colg] = f2bf(y * osc);
        }
      }
    }
  }
}

// ---------------- final GEMM: out = AO * Wu^T + bu, 64x128 tile, 3-buf counted vmcnt ----------------

__global__ __launch_bounds__(256)
void gemm_u64(const u16* __restrict__ A, const u16* __restrict__ Bw,
              float* __restrict__ Of, const float* __restrict__ bias) {
  const int K = 1024, N = 1024;
  __shared__ alignas(16) u16 lA[3][64 * 32];   // 12 KB
  __shared__ alignas(16) u16 lB[3][128 * 32];  // 24 KB
  const int tid = threadIdx.x;
  const int wv = tid >> 6, l = tid & 63, g = l >> 4, c16 = l & 15;
  const int wr = wv >> 1, wc = wv & 1;
  const int m0 = blockIdx.x << 6, n0 = blockIdx.y << 7;

  f32x4 acc[2][4];
  const f32x4 z4 = {0.f, 0.f, 0.f, 0.f};
#pragma unroll
  for (int i = 0; i < 2; ++i)
#pragma unroll
    for (int j = 0; j < 4; ++j) acc[i][j] = z4;

  const int srow = tid >> 2;
  const int sc = (tid & 3) ^ ((srow >> 1) & 3);
  const u16* aSrc = A + (size_t)(m0 + srow) * K + sc * 8;  // srow < 64
  const u16* bSrc = Bw + (size_t)(n0 + srow) * K + sc * 8;
  char* ldA = (char*)lA;
  char* ldB = (char*)lB;
  const int lof = wv * 1024;

#define STAGE_U(bi, kof)                                   \
  {                                                        \
    char* dA = ldA + (bi)*4096 + lof;                      \
    char* dB = ldB + (bi)*8192 + lof;                      \
    GLDS(aSrc + (kof), dA);                                \
    GLDS(bSrc + (kof), dB);                                \
    GLDS(bSrc + (size_t)64 * K + (kof), dB + 4096);        \
  }

  STAGE_U(0, 0);
  STAGE_U(1, 32);
  int cb = 0, sb = 2;
  for (int kt = 0; kt < 32; ++kt) {
    if (kt < 31) {
      asm volatile("s_waitcnt vmcnt(3)" ::: "memory");
    } else {
      asm volatile("s_waitcnt vmcnt(0)" ::: "memory");
    }
    __builtin_amdgcn_s_barrier();
    if (kt + 2 < 32) STAGE_U(sb, (kt + 2) << 5);
    const char* bA = ldA + cb * 4096;
    const char* bB = ldB + cb * 8192;
    bf16x8 af[2], bfr[4];
#pragma unroll
    for (int mi = 0; mi < 2; ++mi) {
      int row = wr * 32 + mi * 16 + c16;
      af[mi] = *(const bf16x8*)(bA + row * 64 + ((g * 16) ^ (((row >> 1) & 3) << 4)));
    }
#pragma unroll
    for (int ni = 0; ni < 4; ++ni) {
      int row = wc * 64 + ni * 16 + c16;
      bfr[ni] = *(const bf16x8*)(bB + row * 64 + ((g * 16) ^ (((row >> 1) & 3) << 4)));
    }
    __builtin_amdgcn_s_setprio(1);
#pragma unroll
    for (int mi = 0; mi < 2; ++mi)
#pragma unroll
      for (int ni = 0; ni < 4; ++ni)
        acc[mi][ni] = mfma16(af[mi], bfr[ni], acc[mi][ni]);
    __builtin_amdgcn_s_setprio(0);
    cb = cb == 2 ? 0 : cb + 1;
    sb = sb == 2 ? 0 : sb + 1;
  }
#undef STAGE_U

#pragma unroll
  for (int ni = 0; ni < 4; ++ni) {
    int col = n0 + wc * 64 + ni * 16 + c16;
    float bv = bias[col];
#pragma unroll
    for (int mi = 0; mi < 2; ++mi) {
      int row = m0 + wr * 32 + mi * 16 + g * 4;
      float* dst = Of + (size_t)row * N + col;
#pragma unroll
      for (int r = 0; r < 4; ++r) dst[(size_t)r * N] = acc[mi][ni][r] + bv;
    }
  }
}

// ---------------- flash attention, 32x32 MFMA, in-block KV-split ----------------
// grid (16, 4, 8) = (h, b, qt): qt SLOWEST -> the 8 qt-blocks of one (b,h) land on
// one XCD (linear ids differ by 64 ≡ 0 mod 8) and share L2-resident K/V.
// block = 512 thr = 8 waves; w4 = wv&3 owns q-rows; kvh2 = wv>>2 = KV parity.
// Combine buffer aliases K/V tiles (union) -> LDS 64 KB -> 2 blocks/CU.

__global__ __launch_bounds__(512, 4)
void attn_kernel(const u16* __restrict__ Q, const u16* __restrict__ Kb,
                 const u16* __restrict__ Vt, u16* __restrict__ AO) {
  __shared__ union alignas(16) {
    struct { u16 K[2][2][4096]; u16 V[2][2][4096]; } kv;  // [kvh2][buf], 64 KB
    float cmb[4][64][34];                                 // used only after the loop
  } sm;
  const int tid = threadIdx.x;
  const int wv = tid >> 6, l = tid & 63;
  const int w4 = wv & 3, kvh2 = wv >> 2;
  const int lq = l & 31, hi = l >> 5;
  const int h = blockIdx.x, b = blockIdx.y, qt = blockIdx.z;
  const int qrow = (b << 10) + (qt << 7) + (w4 << 5) + lq;

  // Q fragments (B-operand): qf[kk] holds d = 16*kk + 8*hi + j, q-row = lq
  const u16* qp = Q + (size_t)qrow * 1024 + h * 64 + hi * 8;
  bf16x8 qf[4];
#pragma unroll
  for (int kk = 0; kk < 4; ++kk) qf[kk] = *(const bf16x8*)(qp + 16 * kk);

  f32x16 acc[2];
#pragma unroll
  for (int d0 = 0; d0 < 2; ++d0)
#pragma unroll
    for (int i = 0; i < 16; ++i) acc[d0][i] = 0.f;
  float m_run = -1e30f, l_run = 0.f;

  // staging sources: K chunk(dc=w4, kv=l), V chunk(kvc=w4, d=l); each parity its own tiles
  const u16* Ksrc = Kb + ((size_t)(b * 2048) + l) * 1024 + h * 64 + w4 * 8;
  const u16* Vsrc = Vt + ((size_t)((b * 16 + h) * 64) + l) * 2048 + w4 * 8;

#define STAGE_KV(bi, it)                                    \
  {                                                         \
    const int kv0 = ((it) << 7) + (kvh2 << 6);              \
    char* dK = (char*)sm.kv.K[kvh2][bi] + w4 * 1024;        \
    char* dV = (char*)sm.kv.V[kvh2][bi] + w4 * 1024;        \
    const u16* ks = Ksrc + (size_t)kv0 * 1024;              \
    const u16* vs = Vsrc + kv0;                             \
    GLDS(ks, dK);                                           \
    GLDS(ks + 32, dK + 4096);                               \
    GLDS(vs, dV);                                           \
    GLDS(vs + 32, dV + 4096);                               \
  }

  STAGE_KV(0, 0);
  __syncthreads();
  int buf = 0;

  for (int it = 0; it < 16; ++it) {
    if (it + 1 < 16) STAGE_KV(buf ^ 1, it + 1);
    const char* bK = (const char*)sm.kv.K[kvh2][buf];
    const char* bV = (const char*)sm.kv.V[kvh2][buf];

    // ---- QK^T ----
    f32x16 s[2];
#pragma unroll
    for (int kvh = 0; kvh < 2; ++kvh)
#pragma unroll
      for (int i = 0; i < 16; ++i) s[kvh][i] = 0.f;
    __builtin_amdgcn_s_setprio(1);
#pragma unroll
    for (int kk = 0; kk < 4; ++kk) {
      const char* kbase = bK + (2 * kk + hi) * 1024;
      bf16x8 kf0 = *(const bf16x8*)(kbase + lq * 16);
      bf16x8 kf1 = *(const bf16x8*)(kbase + (32 + lq) * 16);
      s[0] = mfma32(kf0, qf[kk], s[0]);
      s[1] = mfma32(kf1, qf[kk], s[1]);
    }
    __builtin_amdgcn_s_setprio(0);

    // ---- online softmax (exp2 domain), defer-max THR=8, 4-way-ILP trees ----
    float tm0 = fmaxf(s[0][0], s[1][0]), tm1 = fmaxf(s[0][1], s[1][1]);
    float tm2 = fmaxf(s[0][2], s[1][2]), tm3 = fmaxf(s[0][3], s[1][3]);
#pragma unroll
    for (int i = 4; i < 16; i += 4) {
      tm0 = fmaxf(tm0, fmaxf(s[0][i], s[1][i]));
      tm1 = fmaxf(tm1, fmaxf(s[0][i + 1], s[1][i + 1]));
      tm2 = fmaxf(tm2, fmaxf(s[0][i + 2], s[1][i + 2]));
      tm3 = fmaxf(tm3, fmaxf(s[0][i + 3], s[1][i + 3]));
    }
    float tm = fmaxf(fmaxf(tm0, tm1), fmaxf(tm2, tm3));
    tm = fmaxf(tm, __shfl_xor(tm, 32));
    if (!__all(tm <= m_run + 8.f)) {
      float mnew = fmaxf(m_run, tm);
      float corr = __builtin_amdgcn_exp2f(m_run - mnew);
      l_run *= corr;
#pragma unroll
      for (int d0 = 0; d0 < 2; ++d0)
#pragma unroll
        for (int i = 0; i < 16; ++i) acc[d0][i] *= corr;
      m_run = mnew;
    }
    float ts0 = 0.f, ts1 = 0.f, ts2 = 0.f, ts3 = 0.f;
#pragma unroll
    for (int kvh = 0; kvh < 2; ++kvh)
#pragma unroll
      for (int i = 0; i < 16; i += 4) {
        float p0 = __builtin_amdgcn_exp2f(s[kvh][i] - m_run);
        float p1 = __builtin_amdgcn_exp2f(s[kvh][i + 1] - m_run);
        float p2 = __builtin_amdgcn_exp2f(s[kvh][i + 2] - m_run);
        float p3 = __builtin_amdgcn_exp2f(s[kvh][i + 3] - m_run);
        s[kvh][i] = p0; s[kvh][i + 1] = p1; s[kvh][i + 2] = p2; s[kvh][i + 3] = p3;
        ts0 += p0; ts1 += p1; ts2 += p2; ts3 += p3;
      }
    float ts = (ts0 + ts1) + (ts2 + ts3);
    ts += __shfl_xor(ts, 32);
    l_run += ts;

    // ---- pack P -> bf16 pairs (1 VOP3 each): pk[kvh][kp][tt], kv_local = 8*kp+4*hi+2*tt
    unsigned int pk[2][4][2];
#pragma unroll
    for (int kvh = 0; kvh < 2; ++kvh)
#pragma unroll
      for (int kp = 0; kp < 4; ++kp)
#pragma unroll
        for (int tt = 0; tt < 2; ++tt)
          pk[kvh][kp][tt] = cvt_pk_bf16(s[kvh][4 * kp + 2 * tt], s[kvh][4 * kp + 2 * tt + 1]);

    // ---- PV: per kk build B-frag (P^T) via shfl_xor(32), then 2 mfma ----
    __builtin_amdgcn_s_setprio(1);
#pragma unroll
    for (int kk = 0; kk < 4; ++kk) {
      const int kvh = kk >> 1, kb = kk & 1;
      union { unsigned w[4]; bf16x8 v; } bw;
#pragma unroll
      for (int tt = 0; tt < 2; ++tt) {
        unsigned A0 = pk[kvh][2 * kb][tt];
        unsigned A1 = pk[kvh][2 * kb + 1][tt];
        unsigned S = (unsigned)__shfl_xor((int)(hi ? A0 : A1), 32);
        bw.w[tt] = hi ? S : A0;
        bw.w[2 + tt] = hi ? A1 : S;
      }
      const char* vbase = bV + (2 * kk + hi) * 1024;
      bf16x8 vf0 = *(const bf16x8*)(vbase + lq * 16);
      bf16x8 vf1 = *(const bf16x8*)(vbase + (32 + lq) * 16);
      acc[0] = mfma32(vf0, bw.v, acc[0]);
      acc[1] = mfma32(vf1, bw.v, acc[1]);
    }
    __builtin_amdgcn_s_setprio(0);
    __syncthreads();
    buf ^= 1;
  }
#undef STAGE_KV

  // ---- merge the two KV halves (exact flash combine) through aliased LDS ----
  if (wv >= 4) {
    float* cp = sm.cmb[w4][l];
#pragma unroll
    for (int d0 = 0; d0 < 2; ++d0)
#pragma unroll
      for (int i = 0; i < 16; ++i) cp[d0 * 16 + i] = acc[d0][i];
    cp[32] = m_run;
    cp[33] = l_run;
  }
  __syncthreads();
  if (wv < 4) {
    const float* cp = sm.cmb[w4][l];
    float m1 = cp[32], l1 = cp[33];
    float mm = fmaxf(m_run, m1);
    float c0 = __builtin_amdgcn_exp2f(m_run - mm);
    float c1 = __builtin_amdgcn_exp2f(m1 - mm);
    float invl = 1.f / (l_run * c0 + l1 * c1);
    float s0 = c0 * invl, s1 = c1 * invl;
    // O^T regs -> AO[q][h*64+d], d = 32*d0 + 8*rg + 4*hi + rr
#pragma unroll
    for (int d0 = 0; d0 < 2; ++d0)
#pragma unroll
      for (int rg = 0; rg < 4; ++rg) {
        float v0 = acc[d0][4 * rg + 0] * s0 + cp[d0 * 16 + 4 * rg + 0] * s1;
        float v1 = acc[d0][4 * rg + 1] * s0 + cp[d0 * 16 + 4 * rg + 1] * s1;
        float v2 = acc[d0][4 * rg + 2] * s0 + cp[d0 * 16 + 4 * rg + 2] * s1;
        float v3 = acc[d0][4 * rg + 3] * s0 + cp[d0 * 16 + 4 * rg + 3] * s1;
        u32x2 o;
        o.x = cvt_pk_bf16(v0, v1);
        o.y = cvt_pk_bf16(v2, v3);
        int d = 32 * d0 + 8 * rg + 4 * hi;
        *(u32x2*)(AO + (size_t)qrow * 1024 + h * 64 + d) = o;
      }
  }
}

// ---------------- launch ----------------

extern "C" void kernel_launch(void* const* d_in, const int* in_sizes, int n_in,
                              void* d_out, int out_size, void* d_ws, size_t ws_size,
                              hipStream_t stream) {
  const float* x = (const float*)d_in[0];
  const float* ctx = (const float*)d_in[1];
  const float* Wq = (const float*)d_in[2];
  const float* Wk = (const float*)d_in[3];
  const float* Wv = (const float*)d_in[4];
  const float* Wu = (const float*)d_in[5];
  const float* bu = (const float*)d_in[6];
  const float* qg = (const float*)d_in[7];
  const float* qb = (const float*)d_in[8];
  const float* kg = (const float*)d_in[9];
  const float* kb = (const float*)d_in[10];
  float* out = (float*)d_out;

  char* w = (char*)d_ws;
  u16* XCB = (u16*)(w);                       // 16 MB: xc bf16 [B,T,E]
  u16* WQB = (u16*)(w + ((size_t)16 << 20));  // 8 MB: Wq,Wk,Wv,Wu bf16 contiguous
  u16* QBB = (u16*)(w + ((size_t)24 << 20));  // 8 MB
  u16* KBB = (u16*)(w + ((size_t)32 << 20));  // 16 MB
  u16* VT = (u16*)(w + ((size_t)48 << 20));   // 16 MB
  u16* AO = (u16*)(w + ((size_t)64 << 20));   // 8 MB  (total 72 MB)

  const float invs = 0.17677669529663687f;          // 1024^-0.25
  const float invs_l2e = invs * 1.44269504088896f;  // fold log2(e) into Q for exp2 softmax

  cast_concat<<<2048, 256, 0, stream>>>(x, ctx, XCB);
  cast_w<<<1024, 256, 0, stream>>>(Wq, Wk, Wv, Wu, WQB);

  gemm_qkv<<<dim3(64, 24), 256, 0, stream>>>(XCB, WQB, QBB, KBB, VT,
                                             qg, qb, kg, kb, invs_l2e, invs);

  attn_kernel<<<dim3(16, 4, 8), 512, 0, stream>>>(QBB, KBB, VT, AO);

  gemm_u64<<<dim3(64, 8), 256, 0, stream>>>(AO, WQB + ((size_t)3 << 20), out, bu);
}

// Round 8
// 244.039 us; speedup vs baseline: 1.2094x; 1.0694x over previous
//
#include <hip/hip_runtime.h>
#include <cstdint>

// ContextualAttention on MI355X (gfx950), all-bf16 MFMA pipeline.
// R8: GEMMs = R6's proven 2-phase dbuf skeleton with BK=64 (barriers halved:
//     32->16 drains/K-loop). Coalesced staging via in-row chunk permutation
//     (l&7)^((l>>3)&7); read slot ((kk<<2)+g)^(row&7) -> 2 lanes/bank-quad (free).
//     Counted-vmcnt 3-buf REMOVED (regressed twice: m196 anti-pattern).
//     attn + casts unchanged.

typedef unsigned short u16;
typedef __attribute__((ext_vector_type(8))) short bf16x8;
typedef __attribute__((ext_vector_type(4))) float f32x4;
typedef __attribute__((ext_vector_type(16))) float f32x16;
typedef __attribute__((ext_vector_type(4))) unsigned short u16x4;
typedef __attribute__((ext_vector_type(2))) unsigned int u32x2;

#define GLDS(gsrc, ldst)                                                              \
  __builtin_amdgcn_global_load_lds(                                                   \
      (const __attribute__((address_space(1))) unsigned int*)(gsrc),                  \
      (__attribute__((address_space(3))) unsigned int*)(ldst), 16, 0, 0)

__device__ __forceinline__ u16 f2bf(float x) {
  unsigned int u = __float_as_uint(x);
  u += 0x7fffu + ((u >> 16) & 1u);
  return (u16)(u >> 16);
}

// packed f32x2 -> bf16x2 (RNE), single VOP3 (T12 recipe; no builtin on gfx950)
__device__ __forceinline__ unsigned cvt_pk_bf16(float lo, float hi) {
  unsigned r;
  asm("v_cvt_pk_bf16_f32 %0, %1, %2" : "=v"(r) : "v"(lo), "v"(hi));
  return r;
}

__device__ __forceinline__ f32x4 mfma16(bf16x8 a, bf16x8 b, f32x4 c) {
  return __builtin_amdgcn_mfma_f32_16x16x32_bf16(a, b, c, 0, 0, 0);
}
__device__ __forceinline__ f32x16 mfma32(bf16x8 a, bf16x8 b, f32x16 c) {
  return __builtin_amdgcn_mfma_f32_32x32x16_bf16(a, b, c, 0, 0, 0);
}

// ---------------- cast kernels ----------------

__global__ __launch_bounds__(256) void cast_concat(const float* __restrict__ x,
                                                   const float* __restrict__ c,
                                                   u16* __restrict__ o) {
  const int n4 = (8 << 20) / 4;  // B*T*E / 4
  for (int i = blockIdx.x * blockDim.x + threadIdx.x; i < n4; i += gridDim.x * blockDim.x) {
    int elem = i * 4;
    int b = elem >> 21;
    int rem = elem & ((1 << 21) - 1);
    int r = rem >> 10;
    int e = rem & 1023;
    const float* src = (r < 1024) ? (x + ((((size_t)(b << 10)) + r) << 10) + e)
                                  : (c + ((((size_t)(b << 10)) + (r - 1024)) << 10) + e);
    float4 v = *(const float4*)src;
    u16x4 ov;
    ov.x = f2bf(v.x); ov.y = f2bf(v.y); ov.z = f2bf(v.z); ov.w = f2bf(v.w);
    *(u16x4*)(o + elem) = ov;
  }
}

__global__ __launch_bounds__(256) void cast_w(const float* __restrict__ w0,
                                              const float* __restrict__ w1,
                                              const float* __restrict__ w2,
                                              const float* __restrict__ w3,
                                              u16* __restrict__ o) {
  const int n4 = (4 << 20) / 4;
  for (int i = blockIdx.x * blockDim.x + threadIdx.x; i < n4; i += gridDim.x * blockDim.x) {
    int elem = i * 4;
    int sel = elem >> 20;
    int loc = elem & ((1 << 20) - 1);
    const float* s = (sel == 0) ? w0 : (sel == 1) ? w1 : (sel == 2) ? w2 : w3;
    float4 v = *(const float4*)(s + loc);
    u16x4 ov;
    ov.x = f2bf(v.x); ov.y = f2bf(v.y); ov.z = f2bf(v.z); ov.w = f2bf(v.w);
    *(u16x4*)(o + elem) = ov;
  }
}

// ---------------- merged QKV GEMM: 128x128 tile, BK=64, 2-phase dbuf ----------------
// LDS rows of 128B (K=64). Read slot = ((kk<<2)+g) ^ (row&7): within a quarter-wave
// 16 rows -> 8 slots x 2 lanes = conflict-free. Staging: 8 lanes cover one 128B row
// with chunks permuted by (l&7)^((l>>3)&7) -> coalescing preserved, linear LDS dest.
// grid (64, 24). ny>>3: 0=Q (LN epi, compacted rows), 1=K (LN epi), 2=V (transposed).

__global__ __launch_bounds__(256)
void gemm_qkv(const u16* __restrict__ XCB, const u16* __restrict__ Wall,
              u16* __restrict__ QBB, u16* __restrict__ KBB, u16* __restrict__ VT,
              const float* __restrict__ qg, const float* __restrict__ qb,
              const float* __restrict__ kg, const float* __restrict__ kb,
              float sQ, float sK) {
  const int ny = blockIdx.y;
  const int which = ny >> 3;
  const int m0 = blockIdx.x << 7;
  if (which == 0 && (m0 & 2047) >= 1024) return;  // Q only from x rows
  const int n0 = (ny & 7) << 7;
  const u16* Bw = Wall + ((size_t)which << 20);
  const int K = 1024, N = 1024;

  __shared__ alignas(16) u16 lA[2][128 * 64];  // 32 KB
  __shared__ alignas(16) u16 lB[2][128 * 64];  // 32 KB
  const int tid = threadIdx.x;
  const int wv = tid >> 6, l = tid & 63, g = l >> 4, c16 = l & 15;
  const int wr = wv >> 1, wc = wv & 1;

  f32x4 acc[4][4];
  const f32x4 z4 = {0.f, 0.f, 0.f, 0.f};
#pragma unroll
  for (int i = 0; i < 4; ++i)
#pragma unroll
    for (int j = 0; j < 4; ++j) acc[i][j] = z4;

  // staging: wave writes 1 KB linear (8 rows x 128B); lane -> (row = l>>3, chunk)
  const int srow = (wv << 3) + (l >> 3);        // [0,32) per batch
  const int schk = (l & 7) ^ ((l >> 3) & 7);    // pre-swizzled in-row chunk
  const u16* aSrc = XCB + (size_t)(m0 + srow) * K + schk * 8;
  const u16* bSrc = Bw + (size_t)(n0 + srow) * K + schk * 8;

#define STAGE_G(bi, kof)                                   \
  {                                                        \
    char* dA = (char*)lA + (bi)*16384 + wv * 1024;         \
    char* dB = (char*)lB + (bi)*16384 + wv * 1024;         \
    GLDS(aSrc + (kof), dA);                                \
    GLDS(aSrc + (size_t)32 * K + (kof), dA + 4096);        \
    GLDS(aSrc + (size_t)64 * K + (kof), dA + 8192);        \
    GLDS(aSrc + (size_t)96 * K + (kof), dA + 12288);       \
    GLDS(bSrc + (kof), dB);                                \
    GLDS(bSrc + (size_t)32 * K + (kof), dB + 4096);        \
    GLDS(bSrc + (size_t)64 * K + (kof), dB + 8192);        \
    GLDS(bSrc + (size_t)96 * K + (kof), dB + 12288);       \
  }

  STAGE_G(0, 0);
  __syncthreads();
  int buf = 0;
  for (int kt = 0; kt < 16; ++kt) {
    if (kt + 1 < 16) STAGE_G(buf ^ 1, (kt + 1) << 6);
    const char* bA = (const char*)lA + buf * 16384;
    const char* bB = (const char*)lB + buf * 16384;
#pragma unroll
    for (int kk = 0; kk < 2; ++kk) {
      bf16x8 af[4], bfr[4];
#pragma unroll
      for (int mi = 0; mi < 4; ++mi) {
        int row = wr * 64 + mi * 16 + c16;
        af[mi] = *(const bf16x8*)(bA + row * 128 + ((((kk << 2) + g) ^ (row & 7)) << 4));
      }
#pragma unroll
      for (int ni = 0; ni < 4; ++ni) {
        int row = wc * 64 + ni * 16 + c16;
        bfr[ni] = *(const bf16x8*)(bB + row * 128 + ((((kk << 2) + g) ^ (row & 7)) << 4));
      }
      __builtin_amdgcn_s_setprio(1);
#pragma unroll
      for (int mi = 0; mi < 4; ++mi)
#pragma unroll
        for (int ni = 0; ni < 4; ++ni)
          acc[mi][ni] = mfma16(af[mi], bfr[ni], acc[mi][ni]);
      __builtin_amdgcn_s_setprio(0);
    }
    __syncthreads();
    buf ^= 1;
  }
#undef STAGE_G

  // ---- epilogues ----  C layout: col = l&15, row = (l>>4)*4 + reg
  if (which == 2) {
    // Vt[((b*16+h)*64+d)*2048 + t]; m = b*2048+t, col = h*64+d
#pragma unroll
    for (int ni = 0; ni < 4; ++ni) {
      int col = n0 + wc * 64 + ni * 16 + c16;
      int hh = col >> 6, dd = col & 63;
#pragma unroll
      for (int mi = 0; mi < 4; ++mi) {
        int m = m0 + wr * 64 + mi * 16 + g * 4;
        int bb = m >> 11, tt = m & 2047;
        u16x4 o;
#pragma unroll
        for (int r = 0; r < 4; ++r) o[r] = f2bf(acc[mi][ni][r]);
        *(u16x4*)(VT + ((size_t)((bb * 16 + hh) * 64 + dd)) * 2048 + tt) = o;
      }
    }
  } else {
    const float* G = which ? kg : qg;
    const float* Bt = which ? kb : qb;
    const float osc = which ? sK : sQ;
    u16* Ob = which ? KBB : QBB;
#pragma unroll
    for (int mi = 0; mi < 4; ++mi) {
      float sum[4], sq[4];
#pragma unroll
      for (int r = 0; r < 4; ++r) {
        float s = 0.f, q = 0.f;
#pragma unroll
        for (int ni = 0; ni < 4; ++ni) {
          float v = acc[mi][ni][r];
          s += v;
          q += v * v;
        }
#pragma unroll
        for (int msk = 1; msk < 16; msk <<= 1) {
          s += __shfl_xor(s, msk);
          q += __shfl_xor(q, msk);
        }
        sum[r] = s;
        sq[r] = q;
      }
#pragma unroll
      for (int ni = 0; ni < 4; ++ni) {
        int dloc = ni * 16 + c16;  // head-local (n0, wc*64 are 64-aligned)
        int colg = n0 + wc * 64 + ni * 16 + c16;
        float gv = G[dloc], bv = Bt[dloc];
#pragma unroll
        for (int r = 0; r < 4; ++r) {
          float mean = sum[r] * (1.f / 64.f);
          float var = sq[r] * (1.f / 64.f) - mean * mean;
          float y = (acc[mi][ni][r] - mean) * rsqrtf(var + 1e-5f) * gv + bv;
          int row = m0 + wr * 64 + mi * 16 + g * 4 + r;
          int orow = which ? row : (((row >> 11) << 10) | (row & 1023));
          Ob[(size_t)orow * N + colg] = f2bf(y * osc);
        }
      }
    }
  }
}

// ---------------- final GEMM: out = AO * Wu^T + bu, 64x128 tile, BK=64, 2-phase ----------------

__global__ __launch_bounds__(256)
void gemm_u64(const u16* __restrict__ A, const u16* __restrict__ Bw,
              float* __restrict__ Of, const float* __restrict__ bias) {
  const int K = 1024, N = 1024;
  __shared__ alignas(16) u16 lA[2][64 * 64];   // 16 KB
  __shared__ alignas(16) u16 lB[2][128 * 64];  // 32 KB
  const int tid = threadIdx.x;
  const int wv = tid >> 6, l = tid & 63, g = l >> 4, c16 = l & 15;
  const int wr = wv >> 1, wc = wv & 1;
  const int m0 = blockIdx.x << 6, n0 = blockIdx.y << 7;

  f32x4 acc[2][4];
  const f32x4 z4 = {0.f, 0.f, 0.f, 0.f};
#pragma unroll
  for (int i = 0; i < 2; ++i)
#pragma unroll
    for (int j = 0; j < 4; ++j) acc[i][j] = z4;

  const int srow = (wv << 3) + (l >> 3);
  const int schk = (l & 7) ^ ((l >> 3) & 7);
  const u16* aSrc = A + (size_t)(m0 + srow) * K + schk * 8;
  const u16* bSrc = Bw + (size_t)(n0 + srow) * K + schk * 8;

#define STAGE_U(bi, kof)                                   \
  {                                                        \
    char* dA = (char*)lA + (bi)*8192 + wv * 1024;          \
    char* dB = (char*)lB + (bi)*16384 + wv * 1024;         \
    GLDS(aSrc + (kof), dA);                                \
    GLDS(aSrc + (size_t)32 * K + (kof), dA + 4096);        \
    GLDS(bSrc + (kof), dB);                                \
    GLDS(bSrc + (size_t)32 * K + (kof), dB + 4096);        \
    GLDS(bSrc + (size_t)64 * K + (kof), dB + 8192);        \
    GLDS(bSrc + (size_t)96 * K + (kof), dB + 12288);       \
  }

  STAGE_U(0, 0);
  __syncthreads();
  int buf = 0;
  for (int kt = 0; kt < 16; ++kt) {
    if (kt + 1 < 16) STAGE_U(buf ^ 1, (kt + 1) << 6);
    const char* bA = (const char*)lA + buf * 8192;
    const char* bB = (const char*)lB + buf * 16384;
#pragma unroll
    for (int kk = 0; kk < 2; ++kk) {
      bf16x8 af[2], bfr[4];
#pragma unroll
      for (int mi = 0; mi < 2; ++mi) {
        int row = wr * 32 + mi * 16 + c16;
        af[mi] = *(const bf16x8*)(bA + row * 128 + ((((kk << 2) + g) ^ (row & 7)) << 4));
      }
#pragma unroll
      for (int ni = 0; ni < 4; ++ni) {
        int row = wc * 64 + ni * 16 + c16;
        bfr[ni] = *(const bf16x8*)(bB + row * 128 + ((((kk << 2) + g) ^ (row & 7)) << 4));
      }
      __builtin_amdgcn_s_setprio(1);
#pragma unroll
      for (int mi = 0; mi < 2; ++mi)
#pragma unroll
        for (int ni = 0; ni < 4; ++ni)
          acc[mi][ni] = mfma16(af[mi], bfr[ni], acc[mi][ni]);
      __builtin_amdgcn_s_setprio(0);
    }
    __syncthreads();
    buf ^= 1;
  }
#undef STAGE_U

#pragma unroll
  for (int ni = 0; ni < 4; ++ni) {
    int col = n0 + wc * 64 + ni * 16 + c16;
    float bv = bias[col];
#pragma unroll
    for (int mi = 0; mi < 2; ++mi) {
      int row = m0 + wr * 32 + mi * 16 + g * 4;
      float* dst = Of + (size_t)row * N + col;
#pragma unroll
      for (int r = 0; r < 4; ++r) dst[(size_t)r * N] = acc[mi][ni][r] + bv;
    }
  }
}

// ---------------- flash attention, 32x32 MFMA, in-block KV-split ----------------
// grid (16, 4, 8) = (h, b, qt): qt SLOWEST -> the 8 qt-blocks of one (b,h) land on
// one XCD (linear ids differ by 64 ≡ 0 mod 8) and share L2-resident K/V.
// block = 512 thr = 8 waves; w4 = wv&3 owns q-rows; kvh2 = wv>>2 = KV parity.
// Combine buffer aliases K/V tiles (union) -> LDS 64 KB -> 2 blocks/CU.

__global__ __launch_bounds__(512, 4)
void attn_kernel(const u16* __restrict__ Q, const u16* __restrict__ Kb,
                 const u16* __restrict__ Vt, u16* __restrict__ AO) {
  __shared__ union alignas(16) {
    struct { u16 K[2][2][4096]; u16 V[2][2][4096]; } kv;  // [kvh2][buf], 64 KB
    float cmb[4][64][34];                                 // used only after the loop
  } sm;
  const int tid = threadIdx.x;
  const int wv = tid >> 6, l = tid & 63;
  const int w4 = wv & 3, kvh2 = wv >> 2;
  const int lq = l & 31, hi = l >> 5;
  const int h = blockIdx.x, b = blockIdx.y, qt = blockIdx.z;
  const int qrow = (b << 10) + (qt << 7) + (w4 << 5) + lq;

  // Q fragments (B-operand): qf[kk] holds d = 16*kk + 8*hi + j, q-row = lq
  const u16* qp = Q + (size_t)qrow * 1024 + h * 64 + hi * 8;
  bf16x8 qf[4];
#pragma unroll
  for (int kk = 0; kk < 4; ++kk) qf[kk] = *(const bf16x8*)(qp + 16 * kk);

  f32x16 acc[2];
#pragma unroll
  for (int d0 = 0; d0 < 2; ++d0)
#pragma unroll
    for (int i = 0; i < 16; ++i) acc[d0][i] = 0.f;
  float m_run = -1e30f, l_run = 0.f;

  // staging sources: K chunk(dc=w4, kv=l), V chunk(kvc=w4, d=l); each parity its own tiles
  const u16* Ksrc = Kb + ((size_t)(b * 2048) + l) * 1024 + h * 64 + w4 * 8;
  const u16* Vsrc = Vt + ((size_t)((b * 16 + h) * 64) + l) * 2048 + w4 * 8;

#define STAGE_KV(bi, it)                                    \
  {                                                         \
    const int kv0 = ((it) << 7) + (kvh2 << 6);              \
    char* dK = (char*)sm.kv.K[kvh2][bi] + w4 * 1024;        \
    char* dV = (char*)sm.kv.V[kvh2][bi] + w4 * 1024;        \
    const u16* ks = Ksrc + (size_t)kv0 * 1024;              \
    const u16* vs = Vsrc + kv0;                             \
    GLDS(ks, dK);                                           \
    GLDS(ks + 32, dK + 4096);                               \
    GLDS(vs, dV);                                           \
    GLDS(vs + 32, dV + 4096);                               \
  }

  STAGE_KV(0, 0);
  __syncthreads();
  int buf = 0;

  for (int it = 0; it < 16; ++it) {
    if (it + 1 < 16) STAGE_KV(buf ^ 1, it + 1);
    const char* bK = (const char*)sm.kv.K[kvh2][buf];
    const char* bV = (const char*)sm.kv.V[kvh2][buf];

    // ---- QK^T ----
    f32x16 s[2];
#pragma unroll
    for (int kvh = 0; kvh < 2; ++kvh)
#pragma unroll
      for (int i = 0; i < 16; ++i) s[kvh][i] = 0.f;
    __builtin_amdgcn_s_setprio(1);
#pragma unroll
    for (int kk = 0; kk < 4; ++kk) {
      const char* kbase = bK + (2 * kk + hi) * 1024;
      bf16x8 kf0 = *(const bf16x8*)(kbase + lq * 16);
      bf16x8 kf1 = *(const bf16x8*)(kbase + (32 + lq) * 16);
      s[0] = mfma32(kf0, qf[kk], s[0]);
      s[1] = mfma32(kf1, qf[kk], s[1]);
    }
    __builtin_amdgcn_s_setprio(0);

    // ---- online softmax (exp2 domain), defer-max THR=8, 4-way-ILP trees ----
    float tm0 = fmaxf(s[0][0], s[1][0]), tm1 = fmaxf(s[0][1], s[1][1]);
    float tm2 = fmaxf(s[0][2], s[1][2]), tm3 = fmaxf(s[0][3], s[1][3]);
#pragma unroll
    for (int i = 4; i < 16; i += 4) {
      tm0 = fmaxf(tm0, fmaxf(s[0][i], s[1][i]));
      tm1 = fmaxf(tm1, fmaxf(s[0][i + 1], s[1][i + 1]));
      tm2 = fmaxf(tm2, fmaxf(s[0][i + 2], s[1][i + 2]));
      tm3 = fmaxf(tm3, fmaxf(s[0][i + 3], s[1][i + 3]));
    }
    float tm = fmaxf(fmaxf(tm0, tm1), fmaxf(tm2, tm3));
    tm = fmaxf(tm, __shfl_xor(tm, 32));
    if (!__all(tm <= m_run + 8.f)) {
      float mnew = fmaxf(m_run, tm);
      float corr = __builtin_amdgcn_exp2f(m_run - mnew);
      l_run *= corr;
#pragma unroll
      for (int d0 = 0; d0 < 2; ++d0)
#pragma unroll
        for (int i = 0; i < 16; ++i) acc[d0][i] *= corr;
      m_run = mnew;
    }
    float ts0 = 0.f, ts1 = 0.f, ts2 = 0.f, ts3 = 0.f;
#pragma unroll
    for (int kvh = 0; kvh < 2; ++kvh)
#pragma unroll
      for (int i = 0; i < 16; i += 4) {
        float p0 = __builtin_amdgcn_exp2f(s[kvh][i] - m_run);
        float p1 = __builtin_amdgcn_exp2f(s[kvh][i + 1] - m_run);
        float p2 = __builtin_amdgcn_exp2f(s[kvh][i + 2] - m_run);
        float p3 = __builtin_amdgcn_exp2f(s[kvh][i + 3] - m_run);
        s[kvh][i] = p0; s[kvh][i + 1] = p1; s[kvh][i + 2] = p2; s[kvh][i + 3] = p3;
        ts0 += p0; ts1 += p1; ts2 += p2; ts3 += p3;
      }
    float ts = (ts0 + ts1) + (ts2 + ts3);
    ts += __shfl_xor(ts, 32);
    l_run += ts;

    // ---- pack P -> bf16 pairs (1 VOP3 each): pk[kvh][kp][tt], kv_local = 8*kp+4*hi+2*tt
    unsigned int pk[2][4][2];
#pragma unroll
    for (int kvh = 0; kvh < 2; ++kvh)
#pragma unroll
      for (int kp = 0; kp < 4; ++kp)
#pragma unroll
        for (int tt = 0; tt < 2; ++tt)
          pk[kvh][kp][tt] = cvt_pk_bf16(s[kvh][4 * kp + 2 * tt], s[kvh][4 * kp + 2 * tt + 1]);

    // ---- PV: per kk build B-frag (P^T) via shfl_xor(32), then 2 mfma ----
    __builtin_amdgcn_s_setprio(1);
#pragma unroll
    for (int kk = 0; kk < 4; ++kk) {
      const int kvh = kk >> 1, kb = kk & 1;
      union { unsigned w[4]; bf16x8 v; } bw;
#pragma unroll
      for (int tt = 0; tt < 2; ++tt) {
        unsigned A0 = pk[kvh][2 * kb][tt];
        unsigned A1 = pk[kvh][2 * kb + 1][tt];
        unsigned S = (unsigned)__shfl_xor((int)(hi ? A0 : A1), 32);
        bw.w[tt] = hi ? S : A0;
        bw.w[2 + tt] = hi ? A1 : S;
      }
      const char* vbase = bV + (2 * kk + hi) * 1024;
      bf16x8 vf0 = *(const bf16x8*)(vbase + lq * 16);
      bf16x8 vf1 = *(const bf16x8*)(vbase + (32 + lq) * 16);
      acc[0] = mfma32(vf0, bw.v, acc[0]);
      acc[1] = mfma32(vf1, bw.v, acc[1]);
    }
    __builtin_amdgcn_s_setprio(0);
    __syncthreads();
    buf ^= 1;
  }
#undef STAGE_KV

  // ---- merge the two KV halves (exact flash combine) through aliased LDS ----
  if (wv >= 4) {
    float* cp = sm.cmb[w4][l];
#pragma unroll
    for (int d0 = 0; d0 < 2; ++d0)
#pragma unroll
      for (int i = 0; i < 16; ++i) cp[d0 * 16 + i] = acc[d0][i];
    cp[32] = m_run;
    cp[33] = l_run;
  }
  __syncthreads();
  if (wv < 4) {
    const float* cp = sm.cmb[w4][l];
    float m1 = cp[32], l1 = cp[33];
    float mm = fmaxf(m_run, m1);
    float c0 = __builtin_amdgcn_exp2f(m_run - mm);
    float c1 = __builtin_amdgcn_exp2f(m1 - mm);
    float invl = 1.f / (l_run * c0 + l1 * c1);
    float s0 = c0 * invl, s1 = c1 * invl;
    // O^T regs -> AO[q][h*64+d], d = 32*d0 + 8*rg + 4*hi + rr
#pragma unroll
    for (int d0 = 0; d0 < 2; ++d0)
#pragma unroll
      for (int rg = 0; rg < 4; ++rg) {
        float v0 = acc[d0][4 * rg + 0] * s0 + cp[d0 * 16 + 4 * rg + 0] * s1;
        float v1 = acc[d0][4 * rg + 1] * s0 + cp[d0 * 16 + 4 * rg + 1] * s1;
        float v2 = acc[d0][4 * rg + 2] * s0 + cp[d0 * 16 + 4 * rg + 2] * s1;
        float v3 = acc[d0][4 * rg + 3] * s0 + cp[d0 * 16 + 4 * rg + 3] * s1;
        u32x2 o;
        o.x = cvt_pk_bf16(v0, v1);
        o.y = cvt_pk_bf16(v2, v3);
        int d = 32 * d0 + 8 * rg + 4 * hi;
        *(u32x2*)(AO + (size_t)qrow * 1024 + h * 64 + d) = o;
      }
  }
}

// ---------------- launch ----------------

extern "C" void kernel_launch(void* const* d_in, const int* in_sizes, int n_in,
                              void* d_out, int out_size, void* d_ws, size_t ws_size,
                              hipStream_t stream) {
  const float* x = (const float*)d_in[0];
  const float* ctx = (const float*)d_in[1];
  const float* Wq = (const float*)d_in[2];
  const float* Wk = (const float*)d_in[3];
  const float* Wv = (const float*)d_in[4];
  const float* Wu = (const float*)d_in[5];
  const float* bu = (const float*)d_in[6];
  const float* qg = (const float*)d_in[7];
  const float* qb = (const float*)d_in[8];
  const float* kg = (const float*)d_in[9];
  const float* kb = (const float*)d_in[10];
  float* out = (float*)d_out;

  char* w = (char*)d_ws;
  u16* XCB = (u16*)(w);                       // 16 MB: xc bf16 [B,T,E]
  u16* WQB = (u16*)(w + ((size_t)16 << 20));  // 8 MB: Wq,Wk,Wv,Wu bf16 contiguous
  u16* QBB = (u16*)(w + ((size_t)24 << 20));  // 8 MB
  u16* KBB = (u16*)(w + ((size_t)32 << 20));  // 16 MB
  u16* VT = (u16*)(w + ((size_t)48 << 20));   // 16 MB
  u16* AO = (u16*)(w + ((size_t)64 << 20));   // 8 MB  (total 72 MB)

  const float invs = 0.17677669529663687f;          // 1024^-0.25
  const float invs_l2e = invs * 1.44269504088896f;  // fold log2(e) into Q for exp2 softmax

  cast_concat<<<2048, 256, 0, stream>>>(x, ctx, XCB);
  cast_w<<<1024, 256, 0, stream>>>(Wq, Wk, Wv, Wu, WQB);

  gemm_qkv<<<dim3(64, 24), 256, 0, stream>>>(XCB, WQB, QBB, KBB, VT,
                                             qg, qb, kg, kb, invs_l2e, invs);

  attn_kernel<<<dim3(16, 4, 8), 512, 0, stream>>>(QBB, KBB, VT, AO);

  gemm_u64<<<dim3(64, 8), 256, 0, stream>>>(AO, WQB + ((size_t)3 << 20), out, bu);
}